// Round 3
// baseline (856.746 us; speedup 1.0000x reference)
//
#include <hip/hip_runtime.h>
#include <math.h>

// ASG loss, MI355X. inputs (T,B,L) f32, trans (L,L) f32, targets (B,S) i32,
// input_lengths (B,) i32, target_lengths (B,) i32. Output: scalar mean(full-aligned).
constexpr int T_ = 2048, B_ = 64, L_ = 64, S_ = 256;
constexpr float NEGV = -1e30f;
constexpr float LOG2E = 1.4426950408889634f;
constexpr float LN2 = 0.6931471805599453f;

__device__ __forceinline__ float wave_max64(float v) {
#pragma unroll
  for (int off = 1; off < 64; off <<= 1) v = fmaxf(v, __shfl_xor(v, off, 64));
  return v;
}
__device__ __forceinline__ float wave_sum64(float v) {
#pragma unroll
  for (int off = 1; off < 64; off <<= 1) v += __shfl_xor(v, off, 64);
  return v;
}

// Grid = 128 blocks x 128 threads. Blocks 0..63: fcc scan for batch b (exp
// domain, latency-optimized). Blocks 64..127: fac scan for batch b (log2
// domain). Wave 0 computes; both waves cooperate on LDS staging of input rows
// (32-row chunks, double-pumped through registers). Staging applies the
// domain transform (exp for fcc, *log2e for fac) so the scan chain has no
// transcendentals.
__global__ __launch_bounds__(128) void asg_fused(
    const float* __restrict__ inputs, const float* __restrict__ trans,
    const int* __restrict__ targets, const int* __restrict__ ilen,
    const int* __restrict__ tlenp, float* __restrict__ ws) {
  const int bid = blockIdx.x;
  const int b = bid & 63;
  const bool is_fcc = (bid < 64);
  const int tid = threadIdx.x;
  const int lane = tid & 63;
  const int wv = tid >> 6;

  __shared__ __align__(16) float stage[32 * 64];  // 8 KB, rows t%32
  __shared__ __align__(16) float Ebuf[64];        // fcc: exp-domain state

  const int len = ilen[b];
  const int nc = (len + 31) >> 5;

  float4 rb0, rb1, rb2, rb3;
  auto load_chunk = [&](int t0) {
#pragma unroll
    for (int i = 0; i < 4; ++i) {
      int f = i * 128 + tid;
      int r = t0 + (f >> 4);
      r = min(r, T_ - 1);
      const float4 v = *reinterpret_cast<const float4*>(
          inputs + (size_t)r * (B_ * L_) + b * L_ + (f & 15) * 4);
      if (i == 0) rb0 = v; else if (i == 1) rb1 = v;
      else if (i == 2) rb2 = v; else rb3 = v;
    }
  };
  auto xf = [&](float4 v) -> float4 {
    if (is_fcc) {
      v.x = __expf(v.x); v.y = __expf(v.y); v.z = __expf(v.z); v.w = __expf(v.w);
    } else {
      v.x *= LOG2E; v.y *= LOG2E; v.z *= LOG2E; v.w *= LOG2E;
    }
    return v;
  };
  auto store_chunk = [&]() {
    float4* s4 = reinterpret_cast<float4*>(stage);
    s4[0 * 128 + tid] = xf(rb0);
    s4[1 * 128 + tid] = xf(rb1);
    s4[2 * 128 + tid] = xf(rb2);
    s4[3 * 128 + tid] = xf(rb3);
  };

  load_chunk(0);
  store_chunk();
  __syncthreads();
  load_chunk(32);

  if (is_fcc) {
    if (wv == 0) {
      // ============ FCC: E_t = exp(x_t) * (W E_{t-1}) * sc_t ============
      float W[64];
#pragma unroll
      for (int k4 = 0; k4 < 16; ++k4) {
        float4 t4 = *reinterpret_cast<const float4*>(trans + lane * 64 + k4 * 4);
        W[k4 * 4 + 0] = __expf(t4.x);
        W[k4 * 4 + 1] = __expf(t4.y);
        W[k4 * 4 + 2] = __expf(t4.z);
        W[k4 * 4 + 3] = __expf(t4.w);
      }
      float e0 = stage[lane];           // exp(x_0[lane])
      float mx = wave_max64(e0);        // once, off critical path
      float s0i = __builtin_amdgcn_rcpf(mx);
      float Ecur = e0 * s0i;
      float L = -__logf(s0i);
      Ebuf[lane] = Ecur;
      float sc = 1.0f;                  // scale applied at next step (logged then)

      for (int c = 0; c < nc; ++c) {
        const int tb = (c == 0) ? 1 : c * 32, te = min(len, c * 32 + 32);
        for (int t = tb; t < te; ++t) {
          const float* row = stage + ((t & 31) << 6);
          float ex = row[lane];         // exp(x_t[lane]), off-chain
          L -= __logf(sc);              // log the scale applied this step
          float exs = ex * sc;          // off-chain (sc known since last step)
          float s0 = 0.f, s1 = 0.f, s2 = 0.f, s3 = 0.f;
          float s4 = 0.f, s5 = 0.f, s6 = 0.f, s7 = 0.f;
#pragma unroll
          for (int k = 0; k < 64; k += 8) {
            float4 ea = *reinterpret_cast<const float4*>(Ebuf + k);
            float4 eb = *reinterpret_cast<const float4*>(Ebuf + k + 4);
            s0 = fmaf(W[k + 0], ea.x, s0);
            s1 = fmaf(W[k + 1], ea.y, s1);
            s2 = fmaf(W[k + 2], ea.z, s2);
            s3 = fmaf(W[k + 3], ea.w, s3);
            s4 = fmaf(W[k + 4], eb.x, s4);
            s5 = fmaf(W[k + 5], eb.y, s5);
            s6 = fmaf(W[k + 6], eb.z, s6);
            s7 = fmaf(W[k + 7], eb.w, s7);
          }
          float dot = ((s0 + s1) + (s2 + s3)) + ((s4 + s5) + (s6 + s7));
          float En = exs * dot;
          Ebuf[lane] = En;
          Ecur = En;
          // next step's uniform scale: 1/dot_lane0 (>=0.95*maxE, <=67*maxE,
          // keeps maxE in [e^-5.6, e^9.7] forever -> no overflow, no max-scan)
          float d0 = __uint_as_float(
              __builtin_amdgcn_readfirstlane(__float_as_uint(dot)));
          sc = __builtin_amdgcn_rcpf(d0);
        }
        if (c + 1 < nc) {
          __syncthreads();
          store_chunk();
          load_chunk((c + 2) * 32);
          __syncthreads();
        }
      }
      float ssum = wave_sum64(Ecur);
      if (lane == 0) ws[b] = L + __logf(ssum);  // full[b]
    } else {
      for (int c = 0; c < nc; ++c) {
        if (c + 1 < nc) {
          __syncthreads();
          store_chunk();
          load_chunk((c + 2) * 32);
          __syncthreads();
        }
      }
    }
  } else {
    if (wv == 0) {
      // ============ FAC: 256-state bidiagonal scan, log2 domain ============
      const int tl = tlenp[b];
      int4 t4 = *reinterpret_cast<const int4*>(targets + b * S_ + lane * 4);
      const int tg0 = t4.x, tg1 = t4.y, tg2 = t4.z, tg3 = t4.w;
      const int tgm1 = (lane > 0) ? targets[b * S_ + lane * 4 - 1] : 0;
      const float st0 = trans[tg0 * 64 + tg0] * LOG2E;
      const float st1 = trans[tg1 * 64 + tg1] * LOG2E;
      const float st2 = trans[tg2 * 64 + tg2] * LOG2E;
      const float st3 = trans[tg3 * 64 + tg3] * LOG2E;
      const float mt0 = (lane == 0) ? NEGV : trans[tg0 * 64 + tgm1] * LOG2E;
      const float mt1 = trans[tg1 * 64 + tg0] * LOG2E;
      const float mt2 = trans[tg2 * 64 + tg1] * LOG2E;
      const float mt3 = trans[tg3 * 64 + tg2] * LOG2E;
      float a0 = (lane == 0) ? stage[tg0] : NEGV;  // staged row0 already *log2e
      float a1 = NEGV, a2 = NEGV, a3 = NEGV;

      for (int c = 0; c < nc; ++c) {
        const int tb = (c == 0) ? 1 : c * 32, te = min(len, c * 32 + 32);
        for (int t = tb; t < te; ++t) {
          const float* row = stage + ((t & 31) << 6);
          float e0 = row[tg0], e1 = row[tg1], e2 = row[tg2], e3 = row[tg3];
          float sh0 = __shfl_up(a3, 1, 64);
          if (lane == 0) sh0 = NEGV;
          float u, v, mx, mn;
          u = a0 + st0; v = sh0 + mt0; mx = fmaxf(u, v); mn = fminf(u, v);
          float n0 = e0 + mx + log2f(1.0f + exp2f(mn - mx));
          u = a1 + st1; v = a0 + mt1; mx = fmaxf(u, v); mn = fminf(u, v);
          float n1 = e1 + mx + log2f(1.0f + exp2f(mn - mx));
          u = a2 + st2; v = a1 + mt2; mx = fmaxf(u, v); mn = fminf(u, v);
          float n2 = e2 + mx + log2f(1.0f + exp2f(mn - mx));
          u = a3 + st3; v = a2 + mt3; mx = fmaxf(u, v); mn = fminf(u, v);
          float n3 = e3 + mx + log2f(1.0f + exp2f(mn - mx));
          a0 = n0; a1 = n1; a2 = n2; a3 = n3;
        }
        if (c + 1 < nc) {
          __syncthreads();
          store_chunk();
          load_chunk((c + 2) * 32);
          __syncthreads();
        }
      }
      const int idx = tl - 1;
      if ((idx >> 2) == lane) {
        const int r3 = idx & 3;
        float res = (r3 == 0) ? a0 : (r3 == 1) ? a1 : (r3 == 2) ? a2 : a3;
        ws[B_ + b] = res * LN2;  // back to natural log
      }
    } else {
      for (int c = 0; c < nc; ++c) {
        if (c + 1 < nc) {
          __syncthreads();
          store_chunk();
          load_chunk((c + 2) * 32);
          __syncthreads();
        }
      }
    }
  }
}

__global__ void asg_combine(const float* __restrict__ ws,
                            float* __restrict__ out) {
  const int j = threadIdx.x;  // 64 threads
  float d = ws[j] - ws[B_ + j];
  d = wave_sum64(d);
  if (j == 0) out[0] = d * (1.0f / 64.0f);
}

extern "C" void kernel_launch(void* const* d_in, const int* in_sizes, int n_in,
                              void* d_out, int out_size, void* d_ws,
                              size_t ws_size, hipStream_t stream) {
  const float* inputs = (const float*)d_in[0];
  const float* trans = (const float*)d_in[1];
  const int* targets = (const int*)d_in[2];
  const int* ilen = (const int*)d_in[3];
  const int* tlen = (const int*)d_in[4];
  float* ws = (float*)d_ws;
  float* out = (float*)d_out;

  hipLaunchKernelGGL(asg_fused, dim3(2 * B_), dim3(128), 0, stream,
                     inputs, trans, targets, ilen, tlen, ws);
  hipLaunchKernelGGL(asg_combine, dim3(1), dim3(64), 0, stream, ws, out);
}

// Round 4
// 587.782 us; speedup vs baseline: 1.4576x; 1.4576x over previous
//
#include <hip/hip_runtime.h>
#include <math.h>

// ASG loss, MI355X. inputs (T,B,L) f32, trans (L,L) f32, targets (B,S) i32,
// input_lengths (B,) i32, target_lengths (B,) i32. out = mean(full - aligned).
//
// fcc is computed as a product of 64x64 exp-domain transfer matrices on MFMA:
//   E_t = diag(exp(x_t)) * W * E_{t-1},  W = exp(trans)
// Phase 1 (2048 blocks): per (batch, 64-step segment) compute
//   M_seg = prod Ã_t (bf16, f32 accum), Ã_t = diag(exp(x_t - m_t)) * W,
//   with lag-8 uniform rescale; writes M_seg (bf16) + log-scale to ws.
// Phase 2 (64 blocks): serial matvec scan over 32 segment matrices + LSE.
// fac: exact serial bidiagonal scan (log2 domain), pre-gathered emissions.
// NOTE: needs ~16.8 MB of d_ws.

constexpr int T_ = 2048, B_ = 64, L_ = 64, S_ = 256;
constexpr int CSEG = 64, NSEG = 32;  // segments cover t = 1..2047
constexpr float NEGV = -1e30f;
constexpr float LOG2E = 1.4426950408889634f;
constexpr float LN2 = 0.6931471805599453f;

typedef __bf16 bf16x8 __attribute__((ext_vector_type(8)));
typedef __bf16 bf16x4 __attribute__((ext_vector_type(4)));
typedef float f32x16 __attribute__((ext_vector_type(16)));

constexpr size_t OFF_SCALE = (size_t)NSEG * B_ * 4096 * 2;  // 16 MB of M_seg
constexpr size_t OFF_FULL = OFF_SCALE + (size_t)NSEG * B_ * 4;
constexpr size_t OFF_AL = OFF_FULL + (size_t)B_ * 4;

__device__ __forceinline__ float wave_max64(float v) {
#pragma unroll
  for (int off = 1; off < 64; off <<= 1) v = fmaxf(v, __shfl_xor(v, off, 64));
  return v;
}
__device__ __forceinline__ float wave_sum64(float v) {
#pragma unroll
  for (int off = 1; off < 64; off <<= 1) v += __shfl_xor(v, off, 64);
  return v;
}

struct P1shm {
  __align__(16) float xs[CSEG][64];     // exp(x_t - m_t), 16 KB
  __align__(16) float m_arr[CSEG];
  __align__(16) float redmax[4];
  __align__(16) __bf16 P[2][64 * 68];   // col-major, stride 68 bf16 (136 B)
};
struct FACshm {
  __align__(16) float E[2][16][256];    // gathered emissions * log2e, 32 KB
};
union KU {
  P1shm p1;
  FACshm fac;
};

// K1: blocks 0..63 = fac(batch b); blocks 64..2111 = phase-1 (batch, segment).
__global__ __launch_bounds__(256) void asg_k1(
    const float* __restrict__ inputs, const float* __restrict__ trans,
    const int* __restrict__ targets, const int* __restrict__ ilen,
    const int* __restrict__ tlenp, char* __restrict__ ws) {
  __shared__ KU u;
  const int tid = threadIdx.x, lane = tid & 63, wv = tid >> 6;
  const int bid = blockIdx.x;
  float* scales = (float*)(ws + OFF_SCALE);
  float* alig = (float*)(ws + OFF_AL);

  if (bid < B_) {
    // ======================= FAC (exact, log2 domain) =======================
    const int b = bid;
    const int len = ilen[b];
    const int tl = tlenp[b];

    // stager threads (tid 64..255) own 1-2 target columns
    int c0 = -1, c1 = -1, tgA = 0, tgB = 0;
    if (tid >= 64) {
      c0 = tid - 64;
      c1 = (c0 + 192 < 256) ? c0 + 192 : -1;
      tgA = targets[b * S_ + c0];
      if (c1 >= 0) tgB = targets[b * S_ + c1];
    }
    auto stage = [&](int c, int buf) {
      if (tid < 64) return;
      const float* base = inputs + (size_t)(16 * c) * (B_ * L_) + b * L_;
      for (int r = 0; r < 16; ++r) {
        u.fac.E[buf][r][c0] = base[r * (B_ * L_) + tgA] * LOG2E;
        if (c1 >= 0) u.fac.E[buf][r][c1] = base[r * (B_ * L_) + tgB] * LOG2E;
      }
    };

    // compute-wave setup
    int tg0 = 0, tg1 = 0, tg2 = 0, tg3 = 0;
    float st0 = 0, st1 = 0, st2 = 0, st3 = 0, mt0 = 0, mt1 = 0, mt2 = 0, mt3 = 0;
    float a0 = NEGV, a1 = NEGV, a2 = NEGV, a3 = NEGV;
    if (tid < 64) {
      int4 t4 = *(const int4*)(targets + b * S_ + lane * 4);
      tg0 = t4.x; tg1 = t4.y; tg2 = t4.z; tg3 = t4.w;
      int tgm1 = (lane > 0) ? targets[b * S_ + lane * 4 - 1] : 0;
      st0 = trans[tg0 * 64 + tg0] * LOG2E;
      st1 = trans[tg1 * 64 + tg1] * LOG2E;
      st2 = trans[tg2 * 64 + tg2] * LOG2E;
      st3 = trans[tg3 * 64 + tg3] * LOG2E;
      mt0 = (lane == 0) ? NEGV : trans[tg0 * 64 + tgm1] * LOG2E;
      mt1 = trans[tg1 * 64 + tg0] * LOG2E;
      mt2 = trans[tg2 * 64 + tg1] * LOG2E;
      mt3 = trans[tg3 * 64 + tg2] * LOG2E;
    }
    stage(0, 0);
    __syncthreads();
    if (tid < 64) a0 = (lane == 0) ? u.fac.E[0][0][0] : NEGV;

    for (int c = 0; 16 * c < len; ++c) {
      if (16 * (c + 1) < len) stage(c + 1, (c + 1) & 1);
      if (tid < 64) {
        const int buf = c & 1;
        const int r0 = (c == 0) ? 1 : 0;
        const int rmax = min(16, len - 16 * c);
        for (int r = r0; r < rmax; ++r) {
          float4 e = *(const float4*)&u.fac.E[buf][r][lane * 4];
          float sh0 = __shfl_up(a3, 1, 64);
          if (lane == 0) sh0 = NEGV;
          float uu, vv, mx, mn;
          uu = a0 + st0; vv = sh0 + mt0; mx = fmaxf(uu, vv); mn = fminf(uu, vv);
          float n0 = e.x + mx + log2f(1.0f + exp2f(mn - mx));
          uu = a1 + st1; vv = a0 + mt1; mx = fmaxf(uu, vv); mn = fminf(uu, vv);
          float n1 = e.y + mx + log2f(1.0f + exp2f(mn - mx));
          uu = a2 + st2; vv = a1 + mt2; mx = fmaxf(uu, vv); mn = fminf(uu, vv);
          float n2 = e.z + mx + log2f(1.0f + exp2f(mn - mx));
          uu = a3 + st3; vv = a2 + mt3; mx = fmaxf(uu, vv); mn = fminf(uu, vv);
          float n3 = e.w + mx + log2f(1.0f + exp2f(mn - mx));
          a0 = n0; a1 = n1; a2 = n2; a3 = n3;
        }
      }
      __syncthreads();
    }
    if (tid < 64) {
      const int idx = tl - 1;
      if ((idx >> 2) == lane) {
        const int r3 = idx & 3;
        float res = (r3 == 0) ? a0 : (r3 == 1) ? a1 : (r3 == 2) ? a2 : a3;
        alig[b] = res * LN2;
      }
    }
    return;
  }

  // ========================= PHASE 1 (MFMA) =========================
  const int sid = bid - B_;
  const int b = sid >> 5, s = sid & 31;
  const int t0 = 1 + s * CSEG;
  const int len = ilen[b];
  int ke = min(CSEG, T_ - t0);
  ke = min(ke, len - t0);
  if (ke < 0) ke = 0;

  // stage raw x rows t0..t0+63 (clamped)
#pragma unroll
  for (int i = 0; i < 4; ++i) {
    int f4 = tid + 256 * i;
    int r = f4 >> 4, c4 = f4 & 15;
    int t = t0 + r;
    if (t > T_ - 1) t = T_ - 1;
    float4 v = *(const float4*)(inputs + (size_t)t * (B_ * L_) + b * L_ + c4 * 4);
    *(float4*)(&u.p1.xs[r][c4 * 4]) = v;
  }
  __syncthreads();
  // per-row max
#pragma unroll
  for (int rr = 0; rr < 16; ++rr) {
    int r = wv * 16 + rr;
    float v = wave_max64(u.p1.xs[r][lane]);
    if (lane == 0) u.p1.m_arr[r] = v;
  }
  __syncthreads();
  // exp transform in place: xs = exp(x - m_t) <= 1
#pragma unroll
  for (int i = 0; i < 4; ++i) {
    int f4 = tid + 256 * i;
    int r = f4 >> 4, c4 = f4 & 15;
    float m = u.p1.m_arr[r];
    float4 v = *(float4*)(&u.p1.xs[r][c4 * 4]);
    v.x = __expf(v.x - m); v.y = __expf(v.y - m);
    v.z = __expf(v.z - m); v.w = __expf(v.w - m);
    *(float4*)(&u.p1.xs[r][c4 * 4]) = v;
  }
  // P[0] = I (col-major [n][k], stride 68)
  for (int i = tid; i < 64 * 68; i += 256) u.p1.P[0][i] = (__bf16)0.0f;
  __syncthreads();
  if (tid < 64) u.p1.P[0][tid * 68 + tid] = (__bf16)1.0f;

  // persistent W fragments (f32): wave quadrant (ma, nb)
  const int ma = wv >> 1, nb = wv & 1;
  const int arow = 32 * ma + (lane & 31);
  const int hh = lane >> 5;
  const int coln = 32 * nb + (lane & 31);
  float Wf[4][8];
#pragma unroll
  for (int kc = 0; kc < 4; ++kc) {
    const float* tp = trans + arow * 64 + kc * 16 + hh * 8;
#pragma unroll
    for (int j = 0; j < 8; ++j) Wf[kc][j] = __expf(tp[j]);
  }

  float lsres = 0.0f;
  int cur = 0;
  for (int k = 0; k < ke; ++k) {
    __syncthreads();  // prev-step P writes + (first iter) init visible
    float scf = 1.0f;
    if ((k & 7) == 0 && k != 0) {
      float mm = fmaxf(fmaxf(u.p1.redmax[0], u.p1.redmax[1]),
                       fmaxf(u.p1.redmax[2], u.p1.redmax[3]));
      scf = __builtin_amdgcn_rcpf(mm);
      lsres += __logf(mm);  // uniform across lanes/waves
    }
    const float srow = u.p1.xs[k][arow] * scf;
    bf16x8 A[4], Bf[4];
    const __bf16* Pc = u.p1.P[cur];
#pragma unroll
    for (int kc = 0; kc < 4; ++kc) {
#pragma unroll
      for (int j = 0; j < 8; ++j) A[kc][j] = (__bf16)(Wf[kc][j] * srow);
      const __bf16* p = Pc + coln * 68 + kc * 16 + hh * 8;
      bf16x4 lo = *(const bf16x4*)p;
      bf16x4 hi = *(const bf16x4*)(p + 4);
      Bf[kc] = __builtin_shufflevector(lo, hi, 0, 1, 2, 3, 4, 5, 6, 7);
    }
    f32x16 acc;
#pragma unroll
    for (int e = 0; e < 16; ++e) acc[e] = 0.0f;
    acc = __builtin_amdgcn_mfma_f32_32x32x16_bf16(A[0], Bf[0], acc, 0, 0, 0);
    acc = __builtin_amdgcn_mfma_f32_32x32x16_bf16(A[1], Bf[1], acc, 0, 0, 0);
    acc = __builtin_amdgcn_mfma_f32_32x32x16_bf16(A[2], Bf[2], acc, 0, 0, 0);
    acc = __builtin_amdgcn_mfma_f32_32x32x16_bf16(A[3], Bf[3], acc, 0, 0, 0);
    __bf16* Pn = u.p1.P[cur ^ 1];
#pragma unroll
    for (int q = 0; q < 4; ++q) {
      // D mapping (verified): col=lane&31, row=(r&3)+8*(r>>2)+4*(lane>>5)
      const int i0 = 32 * ma + 8 * q + 4 * hh;
      bf16x4 w;
      w[0] = (__bf16)acc[4 * q + 0]; w[1] = (__bf16)acc[4 * q + 1];
      w[2] = (__bf16)acc[4 * q + 2]; w[3] = (__bf16)acc[4 * q + 3];
      *(bf16x4*)(Pn + coln * 68 + i0) = w;
    }
    if ((k & 7) == 7) {  // block max for next rescale pickup
      float mx = acc[0];
#pragma unroll
      for (int e = 1; e < 16; ++e) mx = fmaxf(mx, acc[e]);
      mx = wave_max64(mx);
      if (lane == 0) u.p1.redmax[wv] = mx;
    }
    cur ^= 1;
  }
  __syncthreads();
  // write M_seg (bf16, layout G[n*64+k] = M[k][n]) + log-scale
  __bf16* G = ((__bf16*)ws) + (size_t)sid * 4096;
  const __bf16* Pf = u.p1.P[cur];
  for (int i = tid; i < 4096; i += 256) G[i] = Pf[(i >> 6) * 68 + (i & 63)];
  if (wv == 0) {
    float mt = (lane < ke) ? u.p1.m_arr[lane] : 0.0f;
    float msum = wave_sum64(mt);
    if (lane == 0) scales[sid] = msum + lsres;
  }
}

// K2: per-batch scan over 32 segment matrices (wave0 compute, wave1 stage).
__global__ __launch_bounds__(128) void asg_k2(const float* __restrict__ inputs,
                                              char* __restrict__ ws) {
  __shared__ __align__(16) float Gl[2][64][68];
  __shared__ __align__(16) float Eb[64];
  const int tid = threadIdx.x, lane = tid & 63, wv = tid >> 6;
  const int b = blockIdx.x;
  const __bf16* M = (const __bf16*)ws;
  const float* scales = (const float*)(ws + OFF_SCALE);
  float* full = (float*)(ws + OFF_FULL);

  auto stage = [&](int s, int buf) {  // Gl[buf][kk=lane][i] = M[i,kk] (f32)
    const __bf16* g = M + ((size_t)(b * NSEG + s)) * 4096 + lane * 64;
#pragma unroll
    for (int q = 0; q < 8; ++q) {
      bf16x8 v = *(const bf16x8*)(g + q * 8);
      float4 f0{(float)v[0], (float)v[1], (float)v[2], (float)v[3]};
      float4 f1{(float)v[4], (float)v[5], (float)v[6], (float)v[7]};
      *(float4*)&Gl[buf][lane][q * 8] = f0;
      *(float4*)&Gl[buf][lane][q * 8 + 4] = f1;
    }
  };

  float E = 0.0f, ls = 0.0f;
  if (wv == 0) {
    float x0 = inputs[b * L_ + lane];  // t = 0 row
    float m0 = wave_max64(x0);
    E = __expf(x0 - m0);
    ls = m0;
    Eb[lane] = E;
  } else {
    stage(0, 0);
  }
  __syncthreads();
  for (int s = 0; s < NSEG; ++s) {
    if (wv == 1 && s + 1 < NSEG) stage(s + 1, (s + 1) & 1);
    if (wv == 0) {
      const int buf = s & 1;
      float ap0 = 0, ap1 = 0, ap2 = 0, ap3 = 0;
#pragma unroll
      for (int k4 = 0; k4 < 16; ++k4) {
        float4 e4 = *(const float4*)&Eb[k4 * 4];
        ap0 = fmaf(Gl[buf][4 * k4 + 0][lane], e4.x, ap0);
        ap1 = fmaf(Gl[buf][4 * k4 + 1][lane], e4.y, ap1);
        ap2 = fmaf(Gl[buf][4 * k4 + 2][lane], e4.z, ap2);
        ap3 = fmaf(Gl[buf][4 * k4 + 3][lane], e4.w, ap3);
      }
      float ap = (ap0 + ap1) + (ap2 + ap3);
      float mx = wave_max64(ap);
      float sc = __builtin_amdgcn_rcpf(mx);
      E = ap * sc;
      Eb[lane] = E;
      ls += __logf(mx) + scales[b * NSEG + s];
    }
    __syncthreads();
  }
  if (wv == 0) {
    float ssum = wave_sum64(E);
    if (lane == 0) full[b] = ls + __logf(ssum);
  }
}

__global__ void asg_k3(const char* __restrict__ ws, float* __restrict__ out) {
  const int j = threadIdx.x;  // 64 threads
  const float* full = (const float*)(ws + OFF_FULL);
  const float* alig = (const float*)(ws + OFF_AL);
  float d = full[j] - alig[j];
  d = wave_sum64(d);
  if (j == 0) out[0] = d * (1.0f / 64.0f);
}

extern "C" void kernel_launch(void* const* d_in, const int* in_sizes, int n_in,
                              void* d_out, int out_size, void* d_ws,
                              size_t ws_size, hipStream_t stream) {
  const float* inputs = (const float*)d_in[0];
  const float* trans = (const float*)d_in[1];
  const int* targets = (const int*)d_in[2];
  const int* ilen = (const int*)d_in[3];
  const int* tlen = (const int*)d_in[4];
  char* ws = (char*)d_ws;
  float* out = (float*)d_out;

  hipLaunchKernelGGL(asg_k1, dim3(B_ + NSEG * B_), dim3(256), 0, stream,
                     inputs, trans, targets, ilen, tlen, ws);
  hipLaunchKernelGGL(asg_k2, dim3(B_), dim3(128), 0, stream, inputs, ws);
  hipLaunchKernelGGL(asg_k3, dim3(1), dim3(64), 0, stream, ws, out);
}

// Round 5
// 586.936 us; speedup vs baseline: 1.4597x; 1.0014x over previous
//
#include <hip/hip_runtime.h>
#include <math.h>

// ASG loss, MI355X. inputs (T,B,L) f32, trans (L,L) f32, targets (B,S) i32,
// input_lengths (B,) i32, target_lengths (B,) i32. out = mean(full - aligned).
//
// fcc: product of 64x64 exp-domain transfer matrices on MFMA (phase 1 =
// 2048 blocks, one per (batch, 64-step segment); phase 2 = per-batch scan).
// fac: exact serial bidiagonal scan in log2 domain, native v_exp/v_log
// transcendentals, pre-gathered emissions double-buffered in LDS.
// NOTE: needs ~16.8 MB of d_ws.

constexpr int T_ = 2048, B_ = 64, L_ = 64, S_ = 256;
constexpr int CSEG = 64, NSEG = 32;  // segments cover t = 1..2047
constexpr float NEGV = -1e30f;
constexpr float LOG2E = 1.4426950408889634f;
constexpr float LN2 = 0.6931471805599453f;

typedef __bf16 bf16x8 __attribute__((ext_vector_type(8)));
typedef __bf16 bf16x4 __attribute__((ext_vector_type(4)));
typedef float f32x16 __attribute__((ext_vector_type(16)));

constexpr size_t OFF_SCALE = (size_t)NSEG * B_ * 4096 * 2;  // 16 MB of M_seg
constexpr size_t OFF_FULL = OFF_SCALE + (size_t)NSEG * B_ * 4;
constexpr size_t OFF_AL = OFF_FULL + (size_t)B_ * 4;

__device__ __forceinline__ float wave_max64(float v) {
#pragma unroll
  for (int off = 1; off < 64; off <<= 1) v = fmaxf(v, __shfl_xor(v, off, 64));
  return v;
}
__device__ __forceinline__ float wave_sum64(float v) {
#pragma unroll
  for (int off = 1; off < 64; off <<= 1) v += __shfl_xor(v, off, 64);
  return v;
}
// native base-2 transcendentals (v_exp_f32 / v_log_f32, single instruction)
__device__ __forceinline__ float ex2(float x) {
  return __builtin_amdgcn_exp2f(x);
}
__device__ __forceinline__ float lg2(float x) {
  return __builtin_amdgcn_logf(x);
}

struct P1shm {
  __align__(16) float xs[CSEG][64];     // exp(x_t - m_t), 16 KB
  __align__(16) float m_arr[CSEG];
  __align__(16) float redmax[4];
  __align__(16) __bf16 P[2][64 * 68];   // col-major, stride 68 bf16 (136 B)
};
struct FACshm {
  __align__(16) float E[2][16][256];    // gathered emissions * log2e, 32 KB
};
union KU {
  P1shm p1;
  FACshm fac;
};

// K1: blocks 0..63 = fac(batch b); blocks 64..2111 = phase-1 (batch, segment).
__global__ __launch_bounds__(256) void asg_k1(
    const float* __restrict__ inputs, const float* __restrict__ trans,
    const int* __restrict__ targets, const int* __restrict__ ilen,
    const int* __restrict__ tlenp, char* __restrict__ ws) {
  __shared__ KU u;
  const int tid = threadIdx.x, lane = tid & 63, wv = tid >> 6;
  const int bid = blockIdx.x;
  float* scales = (float*)(ws + OFF_SCALE);
  float* alig = (float*)(ws + OFF_AL);

  if (bid < B_) {
    // ======================= FAC (exact, log2 domain) =======================
    const int b = bid;
    const int len = ilen[b];
    const int tl = tlenp[b];

    // stager threads (tid 64..255) own 1-2 target columns
    int c0 = -1, c1 = -1, tgA = 0, tgB = 0;
    if (tid >= 64) {
      c0 = tid - 64;
      c1 = (c0 + 192 < 256) ? c0 + 192 : -1;
      tgA = targets[b * S_ + c0];
      if (c1 >= 0) tgB = targets[b * S_ + c1];
    }
    auto stage = [&](int c, int buf) {
      if (tid < 64) return;
      const float* base = inputs + (size_t)(16 * c) * (B_ * L_) + b * L_;
      for (int r = 0; r < 16; ++r) {
        u.fac.E[buf][r][c0] = base[r * (B_ * L_) + tgA] * LOG2E;
        if (c1 >= 0) u.fac.E[buf][r][c1] = base[r * (B_ * L_) + tgB] * LOG2E;
      }
    };

    // compute-wave setup
    int tg0 = 0, tg1 = 0, tg2 = 0, tg3 = 0;
    float st0 = 0, st1 = 0, st2 = 0, st3 = 0, mt0 = 0, mt1 = 0, mt2 = 0, mt3 = 0;
    float a0 = NEGV, a1 = NEGV, a2 = NEGV, a3 = NEGV;
    if (tid < 64) {
      int4 t4 = *(const int4*)(targets + b * S_ + lane * 4);
      tg0 = t4.x; tg1 = t4.y; tg2 = t4.z; tg3 = t4.w;
      int tgm1 = (lane > 0) ? targets[b * S_ + lane * 4 - 1] : 0;
      st0 = trans[tg0 * 64 + tg0] * LOG2E;
      st1 = trans[tg1 * 64 + tg1] * LOG2E;
      st2 = trans[tg2 * 64 + tg2] * LOG2E;
      st3 = trans[tg3 * 64 + tg3] * LOG2E;
      mt0 = (lane == 0) ? NEGV : trans[tg0 * 64 + tgm1] * LOG2E;
      mt1 = trans[tg1 * 64 + tg0] * LOG2E;
      mt2 = trans[tg2 * 64 + tg1] * LOG2E;
      mt3 = trans[tg3 * 64 + tg2] * LOG2E;
    }
    stage(0, 0);
    __syncthreads();
    if (tid < 64) a0 = (lane == 0) ? u.fac.E[0][0][0] : NEGV;

    for (int c = 0; 16 * c < len; ++c) {
      if (16 * (c + 1) < len) stage(c + 1, (c + 1) & 1);
      if (tid < 64) {
        const int buf = c & 1;
        const int r0 = (c == 0) ? 1 : 0;
        const int rmax = min(16, len - 16 * c);
        float4 e = *(const float4*)&u.fac.E[buf][r0][lane * 4];
        for (int r = r0; r < rmax; ++r) {
          const int rn = (r + 1 < 16) ? r + 1 : r;
          float4 enx = *(const float4*)&u.fac.E[buf][rn][lane * 4];
          float sh0 = __shfl_up(a3, 1, 64);
          if (lane == 0) sh0 = NEGV;
          float uu, vv, mx, mn;
          uu = a0 + st0; vv = sh0 + mt0; mx = fmaxf(uu, vv); mn = fminf(uu, vv);
          float n0 = e.x + mx + lg2(1.0f + ex2(mn - mx));
          uu = a1 + st1; vv = a0 + mt1; mx = fmaxf(uu, vv); mn = fminf(uu, vv);
          float n1 = e.y + mx + lg2(1.0f + ex2(mn - mx));
          uu = a2 + st2; vv = a1 + mt2; mx = fmaxf(uu, vv); mn = fminf(uu, vv);
          float n2 = e.z + mx + lg2(1.0f + ex2(mn - mx));
          uu = a3 + st3; vv = a2 + mt3; mx = fmaxf(uu, vv); mn = fminf(uu, vv);
          float n3 = e.w + mx + lg2(1.0f + ex2(mn - mx));
          a0 = n0; a1 = n1; a2 = n2; a3 = n3;
          e = enx;
        }
      }
      __syncthreads();
    }
    if (tid < 64) {
      const int idx = tl - 1;
      if ((idx >> 2) == lane) {
        const int r3 = idx & 3;
        float res = (r3 == 0) ? a0 : (r3 == 1) ? a1 : (r3 == 2) ? a2 : a3;
        alig[b] = res * LN2;
      }
    }
    return;
  }

  // ========================= PHASE 1 (MFMA) =========================
  const int sid = bid - B_;
  const int b = sid >> 5, s = sid & 31;
  const int t0 = 1 + s * CSEG;
  const int len = ilen[b];
  int ke = min(CSEG, T_ - t0);
  ke = min(ke, len - t0);
  if (ke < 0) ke = 0;

  // stage raw x rows t0..t0+63 (clamped)
#pragma unroll
  for (int i = 0; i < 4; ++i) {
    int f4 = tid + 256 * i;
    int r = f4 >> 4, c4 = f4 & 15;
    int t = t0 + r;
    if (t > T_ - 1) t = T_ - 1;
    float4 v = *(const float4*)(inputs + (size_t)t * (B_ * L_) + b * L_ + c4 * 4);
    *(float4*)(&u.p1.xs[r][c4 * 4]) = v;
  }
  __syncthreads();
  // per-row max
#pragma unroll
  for (int rr = 0; rr < 16; ++rr) {
    int r = wv * 16 + rr;
    float v = wave_max64(u.p1.xs[r][lane]);
    if (lane == 0) u.p1.m_arr[r] = v;
  }
  __syncthreads();
  // exp transform in place: xs = exp(x - m_t) <= 1
#pragma unroll
  for (int i = 0; i < 4; ++i) {
    int f4 = tid + 256 * i;
    int r = f4 >> 4, c4 = f4 & 15;
    float m = u.p1.m_arr[r];
    float4 v = *(float4*)(&u.p1.xs[r][c4 * 4]);
    v.x = __expf(v.x - m); v.y = __expf(v.y - m);
    v.z = __expf(v.z - m); v.w = __expf(v.w - m);
    *(float4*)(&u.p1.xs[r][c4 * 4]) = v;
  }
  // P[0] = I (col-major [n][k], stride 68)
  for (int i = tid; i < 64 * 68; i += 256) u.p1.P[0][i] = (__bf16)0.0f;
  __syncthreads();
  if (tid < 64) u.p1.P[0][tid * 68 + tid] = (__bf16)1.0f;

  // persistent W fragments (f32): wave quadrant (ma, nb)
  const int ma = wv >> 1, nb = wv & 1;
  const int arow = 32 * ma + (lane & 31);
  const int hh = lane >> 5;
  const int coln = 32 * nb + (lane & 31);
  float Wf[4][8];
#pragma unroll
  for (int kc = 0; kc < 4; ++kc) {
    const float* tp = trans + arow * 64 + kc * 16 + hh * 8;
#pragma unroll
    for (int j = 0; j < 8; ++j) Wf[kc][j] = __expf(tp[j]);
  }

  float lsres = 0.0f;
  int cur = 0;
  for (int k = 0; k < ke; ++k) {
    __syncthreads();  // prev-step P writes + (first iter) init visible
    float scf = 1.0f;
    if ((k & 7) == 0 && k != 0) {
      float mm = fmaxf(fmaxf(u.p1.redmax[0], u.p1.redmax[1]),
                       fmaxf(u.p1.redmax[2], u.p1.redmax[3]));
      scf = __builtin_amdgcn_rcpf(mm);
      lsres += __logf(mm);  // uniform across lanes/waves
    }
    const float srow = u.p1.xs[k][arow] * scf;
    bf16x8 A[4], Bf[4];
    const __bf16* Pc = u.p1.P[cur];
#pragma unroll
    for (int kc = 0; kc < 4; ++kc) {
#pragma unroll
      for (int j = 0; j < 8; ++j) A[kc][j] = (__bf16)(Wf[kc][j] * srow);
      const __bf16* p = Pc + coln * 68 + kc * 16 + hh * 8;
      bf16x4 lo = *(const bf16x4*)p;
      bf16x4 hi = *(const bf16x4*)(p + 4);
      Bf[kc] = __builtin_shufflevector(lo, hi, 0, 1, 2, 3, 4, 5, 6, 7);
    }
    f32x16 acc;
#pragma unroll
    for (int e = 0; e < 16; ++e) acc[e] = 0.0f;
    acc = __builtin_amdgcn_mfma_f32_32x32x16_bf16(A[0], Bf[0], acc, 0, 0, 0);
    acc = __builtin_amdgcn_mfma_f32_32x32x16_bf16(A[1], Bf[1], acc, 0, 0, 0);
    acc = __builtin_amdgcn_mfma_f32_32x32x16_bf16(A[2], Bf[2], acc, 0, 0, 0);
    acc = __builtin_amdgcn_mfma_f32_32x32x16_bf16(A[3], Bf[3], acc, 0, 0, 0);
    __bf16* Pn = u.p1.P[cur ^ 1];
#pragma unroll
    for (int q = 0; q < 4; ++q) {
      // D mapping (verified): col=lane&31, row=(r&3)+8*(r>>2)+4*(lane>>5)
      const int i0 = 32 * ma + 8 * q + 4 * hh;
      bf16x4 w;
      w[0] = (__bf16)acc[4 * q + 0]; w[1] = (__bf16)acc[4 * q + 1];
      w[2] = (__bf16)acc[4 * q + 2]; w[3] = (__bf16)acc[4 * q + 3];
      *(bf16x4*)(Pn + coln * 68 + i0) = w;
    }
    if ((k & 7) == 7) {  // block max for next rescale pickup
      float mx = acc[0];
#pragma unroll
      for (int e = 1; e < 16; ++e) mx = fmaxf(mx, acc[e]);
      mx = wave_max64(mx);
      if (lane == 0) u.p1.redmax[wv] = mx;
    }
    cur ^= 1;
  }
  __syncthreads();
  // write M_seg (bf16, layout G[n*64+k] = M[k][n]) + log-scale
  __bf16* G = ((__bf16*)ws) + (size_t)sid * 4096;
  const __bf16* Pf = u.p1.P[cur];
  for (int i = tid; i < 4096; i += 256) G[i] = Pf[(i >> 6) * 68 + (i & 63)];
  if (wv == 0) {
    float mt = (lane < ke) ? u.p1.m_arr[lane] : 0.0f;
    float msum = wave_sum64(mt);
    if (lane == 0) scales[sid] = msum + lsres;
  }
}

// K2: per-batch scan over 32 segment matrices (wave0 compute, wave1 stage).
__global__ __launch_bounds__(128) void asg_k2(const float* __restrict__ inputs,
                                              char* __restrict__ ws) {
  __shared__ __align__(16) float Gl[2][64][68];
  __shared__ __align__(16) float Eb[64];
  const int tid = threadIdx.x, lane = tid & 63, wv = tid >> 6;
  const int b = blockIdx.x;
  const __bf16* M = (const __bf16*)ws;
  const float* scales = (const float*)(ws + OFF_SCALE);
  float* full = (float*)(ws + OFF_FULL);

  auto stage = [&](int s, int buf) {  // Gl[buf][kk=lane][i] = M[i,kk] (f32)
    const __bf16* g = M + ((size_t)(b * NSEG + s)) * 4096 + lane * 64;
#pragma unroll
    for (int q = 0; q < 8; ++q) {
      bf16x8 v = *(const bf16x8*)(g + q * 8);
      float4 f0{(float)v[0], (float)v[1], (float)v[2], (float)v[3]};
      float4 f1{(float)v[4], (float)v[5], (float)v[6], (float)v[7]};
      *(float4*)&Gl[buf][lane][q * 8] = f0;
      *(float4*)&Gl[buf][lane][q * 8 + 4] = f1;
    }
  };

  float E = 0.0f, ls = 0.0f;
  if (wv == 0) {
    float x0 = inputs[b * L_ + lane];  // t = 0 row
    float m0 = wave_max64(x0);
    E = __expf(x0 - m0);
    ls = m0;
    Eb[lane] = E;
  } else {
    stage(0, 0);
  }
  __syncthreads();
  for (int s = 0; s < NSEG; ++s) {
    if (wv == 1 && s + 1 < NSEG) stage(s + 1, (s + 1) & 1);
    if (wv == 0) {
      const int buf = s & 1;
      float ap0 = 0, ap1 = 0, ap2 = 0, ap3 = 0;
#pragma unroll
      for (int k4 = 0; k4 < 16; ++k4) {
        float4 e4 = *(const float4*)&Eb[k4 * 4];
        ap0 = fmaf(Gl[buf][4 * k4 + 0][lane], e4.x, ap0);
        ap1 = fmaf(Gl[buf][4 * k4 + 1][lane], e4.y, ap1);
        ap2 = fmaf(Gl[buf][4 * k4 + 2][lane], e4.z, ap2);
        ap3 = fmaf(Gl[buf][4 * k4 + 3][lane], e4.w, ap3);
      }
      float ap = (ap0 + ap1) + (ap2 + ap3);
      float mx = wave_max64(ap);
      float sc = __builtin_amdgcn_rcpf(mx);
      E = ap * sc;
      Eb[lane] = E;
      ls += __logf(mx) + scales[b * NSEG + s];
    }
    __syncthreads();
  }
  if (wv == 0) {
    float ssum = wave_sum64(E);
    if (lane == 0) full[b] = ls + __logf(ssum);
  }
}

__global__ void asg_k3(const char* __restrict__ ws, float* __restrict__ out) {
  const int j = threadIdx.x;  // 64 threads
  const float* full = (const float*)(ws + OFF_FULL);
  const float* alig = (const float*)(ws + OFF_AL);
  float d = full[j] - alig[j];
  d = wave_sum64(d);
  if (j == 0) out[0] = d * (1.0f / 64.0f);
}

extern "C" void kernel_launch(void* const* d_in, const int* in_sizes, int n_in,
                              void* d_out, int out_size, void* d_ws,
                              size_t ws_size, hipStream_t stream) {
  const float* inputs = (const float*)d_in[0];
  const float* trans = (const float*)d_in[1];
  const int* targets = (const int*)d_in[2];
  const int* ilen = (const int*)d_in[3];
  const int* tlen = (const int*)d_in[4];
  char* ws = (char*)d_ws;
  float* out = (float*)d_out;

  hipLaunchKernelGGL(asg_k1, dim3(B_ + NSEG * B_), dim3(256), 0, stream,
                     inputs, trans, targets, ilen, tlen, ws);
  hipLaunchKernelGGL(asg_k2, dim3(B_), dim3(128), 0, stream, inputs, ws);
  hipLaunchKernelGGL(asg_k3, dim3(1), dim3(64), 0, stream, ws, out);
}

// Round 6
// 431.321 us; speedup vs baseline: 1.9863x; 1.3608x over previous
//
#include <hip/hip_runtime.h>
#include <math.h>

// ASG loss, MI355X. inputs (T,B,L) f32, trans (L,L) f32, targets (B,S) i32,
// input_lengths (B,) i32, target_lengths (B,) i32. out = mean(full - aligned).
//
// asg_p1 (2048 blocks): fcc 64-step segment transfer-matrix products on MFMA.
// asg_fac (64 blocks): exact serial bidiagonal scan, log2 domain; carried
//   chain = one lse (n3 computed first, ds_bpermute result consumed next step).
// asg_k2 (64 blocks): per-batch scan over 32 segment matrices + LSE.
// asg_k3: combine. NOTE: needs ~16.8 MB of d_ws.

constexpr int T_ = 2048, B_ = 64, L_ = 64, S_ = 256;
constexpr int CSEG = 64, NSEG = 32;  // fcc segments cover t = 1..2047
constexpr int FCH = 32;              // fac chunk rows
constexpr float NEGV = -1e30f;
constexpr float LOG2E = 1.4426950408889634f;
constexpr float LN2 = 0.6931471805599453f;

typedef __bf16 bf16x8 __attribute__((ext_vector_type(8)));
typedef __bf16 bf16x4 __attribute__((ext_vector_type(4)));
typedef float f32x16 __attribute__((ext_vector_type(16)));

constexpr size_t OFF_SCALE = (size_t)NSEG * B_ * 4096 * 2;  // 16 MB of M_seg
constexpr size_t OFF_FULL = OFF_SCALE + (size_t)NSEG * B_ * 4;
constexpr size_t OFF_AL = OFF_FULL + (size_t)B_ * 4;

__device__ __forceinline__ float wave_max64(float v) {
#pragma unroll
  for (int off = 1; off < 64; off <<= 1) v = fmaxf(v, __shfl_xor(v, off, 64));
  return v;
}
__device__ __forceinline__ float wave_sum64(float v) {
#pragma unroll
  for (int off = 1; off < 64; off <<= 1) v += __shfl_xor(v, off, 64);
  return v;
}
__device__ __forceinline__ float ex2(float x) {
  return __builtin_amdgcn_exp2f(x);  // raw v_exp_f32
}
__device__ __forceinline__ float lg2(float x) {
  return __builtin_amdgcn_logf(x);   // raw v_log_f32
}
// log2-domain logaddexp of two finite values
__device__ __forceinline__ float lse2(float u, float v) {
  float mx = fmaxf(u, v), mn = fminf(u, v);
  return mx + lg2(1.0f + ex2(mn - mx));
}

// ======================= FAC: exact bidiagonal scan =======================
// 64 blocks x 128 threads. Wave 0: compute (lane holds states 4l..4l+3).
// Wave 1: stage 32 input rows/chunk, coalesced float4, pre-scaled by log2e.
__global__ __launch_bounds__(128) void asg_fac(
    const float* __restrict__ inputs, const float* __restrict__ trans,
    const int* __restrict__ targets, const int* __restrict__ ilen,
    const int* __restrict__ tlenp, char* __restrict__ ws) {
  __shared__ __align__(16) float E[2][FCH][64];
  const int tid = threadIdx.x, lane = tid & 63, wv = tid >> 6;
  const int b = blockIdx.x;
  const int len = ilen[b];
  const int tl = tlenp[b];
  float* alig = (float*)(ws + OFF_AL);

  auto stage = [&](int c, int buf) {  // wave 1 only
    const float* base = inputs + (size_t)(c * FCH) * (B_ * L_) + b * L_;
#pragma unroll
    for (int i = 0; i < 8; ++i) {
      int f4 = lane + 64 * i;  // 512 float4 per chunk
      int r = f4 >> 4, c4 = f4 & 15;
      float4 v = *(const float4*)(base + (size_t)r * (B_ * L_) + c4 * 4);
      v.x *= LOG2E; v.y *= LOG2E; v.z *= LOG2E; v.w *= LOG2E;
      *(float4*)&E[buf][r][c4 * 4] = v;
    }
  };

  // compute-wave constants
  int tg0 = 0, tg1 = 0, tg2 = 0, tg3 = 0;
  float st0 = 0, st1 = 0, st2 = 0, st3 = 0, mt0 = 0, mt1 = 0, mt2 = 0, mt3 = 0;
  if (wv == 0) {
    int4 t4 = *(const int4*)(targets + b * S_ + lane * 4);
    tg0 = t4.x; tg1 = t4.y; tg2 = t4.z; tg3 = t4.w;
    int tgm1 = (lane > 0) ? targets[b * S_ + lane * 4 - 1] : 0;
    st0 = trans[tg0 * 64 + tg0] * LOG2E;
    st1 = trans[tg1 * 64 + tg1] * LOG2E;
    st2 = trans[tg2 * 64 + tg2] * LOG2E;
    st3 = trans[tg3 * 64 + tg3] * LOG2E;
    mt0 = (lane == 0) ? NEGV : trans[tg0 * 64 + tgm1] * LOG2E;
    mt1 = trans[tg1 * 64 + tg0] * LOG2E;
    mt2 = trans[tg2 * 64 + tg1] * LOG2E;
    mt3 = trans[tg3 * 64 + tg2] * LOG2E;
  } else {
    stage(0, 0);
  }
  __syncthreads();

  float a0 = NEGV, a1 = NEGV, a2 = NEGV, a3 = NEGV;
  float shv = NEGV;  // alpha[s-1] from previous step (cross-lane)
  const int addr_up = ((lane + 63) & 63) << 2;
  if (wv == 0) a0 = (lane == 0) ? E[0][0][tg0] : NEGV;  // alpha0[:,0]

  for (int c = 0; c * FCH < len; ++c) {
    const int buf = c & 1;
    if (wv == 1) {
      if ((c + 1) * FCH < len) stage(c + 1, buf ^ 1);
    } else {
      const int r0 = (c == 0) ? 1 : 0;
      const int rmax = min(FCH, len - c * FCH);
      float e0 = E[buf][r0][tg0], e1 = E[buf][r0][tg1];
      float e2 = E[buf][r0][tg2], e3 = E[buf][r0][tg3];
      for (int r = r0; r < rmax; ++r) {
        float p0, p1, p2, p3;
        const int rn = (r + 1 < rmax) ? r + 1 : r;  // prefetch next row
        p0 = E[buf][rn][tg0]; p1 = E[buf][rn][tg1];
        p2 = E[buf][rn][tg2]; p3 = E[buf][rn][tg3];
        // carried chain = this lse only (n3 -> n3)
        float n3 = e3 + lse2(a3 + st3, a2 + mt3);
        float shn = __int_as_float(
            __builtin_amdgcn_ds_bpermute(addr_up, __float_as_int(n3)));
        float n0 = e0 + lse2(a0 + st0, shv + mt0);
        float n1 = e1 + lse2(a1 + st1, a0 + mt1);
        float n2 = e2 + lse2(a2 + st2, a1 + mt2);
        a0 = n0; a1 = n1; a2 = n2; a3 = n3;
        shv = (lane == 0) ? NEGV : shn;  // consumed next step -> off-chain
        e0 = p0; e1 = p1; e2 = p2; e3 = p3;
      }
    }
    __syncthreads();
  }
  if (wv == 0) {
    const int idx = tl - 1;
    if ((idx >> 2) == lane) {
      const int r3 = idx & 3;
      float res = (r3 == 0) ? a0 : (r3 == 1) ? a1 : (r3 == 2) ? a2 : a3;
      alig[b] = res * LN2;
    }
  }
}

// ========================= PHASE 1 (MFMA) =========================
struct P1shm {
  __align__(16) float xs[CSEG][64];
  __align__(16) float m_arr[CSEG];
  __align__(16) float redmax[4];
  __align__(16) __bf16 P[2][64 * 68];  // col-major, stride 68
};

__global__ __launch_bounds__(256) void asg_p1(
    const float* __restrict__ inputs, const float* __restrict__ trans,
    const int* __restrict__ ilen, char* __restrict__ ws) {
  __shared__ P1shm u;
  const int tid = threadIdx.x, lane = tid & 63, wv = tid >> 6;
  const int sid = blockIdx.x;
  const int b = sid >> 5, s = sid & 31;
  const int t0 = 1 + s * CSEG;
  const int len = ilen[b];
  float* scales = (float*)(ws + OFF_SCALE);
  int ke = min(CSEG, T_ - t0);
  ke = min(ke, len - t0);
  if (ke < 0) ke = 0;

#pragma unroll
  for (int i = 0; i < 4; ++i) {
    int f4 = tid + 256 * i;
    int r = f4 >> 4, c4 = f4 & 15;
    int t = t0 + r;
    if (t > T_ - 1) t = T_ - 1;
    float4 v = *(const float4*)(inputs + (size_t)t * (B_ * L_) + b * L_ + c4 * 4);
    *(float4*)(&u.xs[r][c4 * 4]) = v;
  }
  __syncthreads();
#pragma unroll
  for (int rr = 0; rr < 16; ++rr) {
    int r = wv * 16 + rr;
    float v = wave_max64(u.xs[r][lane]);
    if (lane == 0) u.m_arr[r] = v;
  }
  __syncthreads();
#pragma unroll
  for (int i = 0; i < 4; ++i) {
    int f4 = tid + 256 * i;
    int r = f4 >> 4, c4 = f4 & 15;
    float m = u.m_arr[r];
    float4 v = *(float4*)(&u.xs[r][c4 * 4]);
    v.x = __expf(v.x - m); v.y = __expf(v.y - m);
    v.z = __expf(v.z - m); v.w = __expf(v.w - m);
    *(float4*)(&u.xs[r][c4 * 4]) = v;
  }
  for (int i = tid; i < 64 * 68; i += 256) u.P[0][i] = (__bf16)0.0f;
  __syncthreads();
  if (tid < 64) u.P[0][tid * 68 + tid] = (__bf16)1.0f;

  const int ma = wv >> 1, nb = wv & 1;
  const int arow = 32 * ma + (lane & 31);
  const int hh = lane >> 5;
  const int coln = 32 * nb + (lane & 31);
  float Wf[4][8];
#pragma unroll
  for (int kc = 0; kc < 4; ++kc) {
    const float* tp = trans + arow * 64 + kc * 16 + hh * 8;
#pragma unroll
    for (int j = 0; j < 8; ++j) Wf[kc][j] = __expf(tp[j]);
  }

  float lsres = 0.0f;
  int cur = 0;
  for (int k = 0; k < ke; ++k) {
    __syncthreads();
    float scf = 1.0f;
    if ((k & 7) == 0 && k != 0) {
      float mm = fmaxf(fmaxf(u.redmax[0], u.redmax[1]),
                       fmaxf(u.redmax[2], u.redmax[3]));
      scf = __builtin_amdgcn_rcpf(mm);
      lsres += __logf(mm);
    }
    const float srow = u.xs[k][arow] * scf;
    bf16x8 A[4], Bf[4];
    const __bf16* Pc = u.P[cur];
#pragma unroll
    for (int kc = 0; kc < 4; ++kc) {
#pragma unroll
      for (int j = 0; j < 8; ++j) A[kc][j] = (__bf16)(Wf[kc][j] * srow);
      const __bf16* p = Pc + coln * 68 + kc * 16 + hh * 8;
      bf16x4 lo = *(const bf16x4*)p;
      bf16x4 hi = *(const bf16x4*)(p + 4);
      Bf[kc] = __builtin_shufflevector(lo, hi, 0, 1, 2, 3, 4, 5, 6, 7);
    }
    f32x16 acc;
#pragma unroll
    for (int e = 0; e < 16; ++e) acc[e] = 0.0f;
    acc = __builtin_amdgcn_mfma_f32_32x32x16_bf16(A[0], Bf[0], acc, 0, 0, 0);
    acc = __builtin_amdgcn_mfma_f32_32x32x16_bf16(A[1], Bf[1], acc, 0, 0, 0);
    acc = __builtin_amdgcn_mfma_f32_32x32x16_bf16(A[2], Bf[2], acc, 0, 0, 0);
    acc = __builtin_amdgcn_mfma_f32_32x32x16_bf16(A[3], Bf[3], acc, 0, 0, 0);
    __bf16* Pn = u.P[cur ^ 1];
#pragma unroll
    for (int q = 0; q < 4; ++q) {
      const int i0 = 32 * ma + 8 * q + 4 * hh;
      bf16x4 w;
      w[0] = (__bf16)acc[4 * q + 0]; w[1] = (__bf16)acc[4 * q + 1];
      w[2] = (__bf16)acc[4 * q + 2]; w[3] = (__bf16)acc[4 * q + 3];
      *(bf16x4*)(Pn + coln * 68 + i0) = w;
    }
    if ((k & 7) == 7) {
      float mx = acc[0];
#pragma unroll
      for (int e = 1; e < 16; ++e) mx = fmaxf(mx, acc[e]);
      mx = wave_max64(mx);
      if (lane == 0) u.redmax[wv] = mx;
    }
    cur ^= 1;
  }
  __syncthreads();
  __bf16* G = ((__bf16*)ws) + (size_t)sid * 4096;
  const __bf16* Pf = u.P[cur];
  for (int i = tid; i < 4096; i += 256) G[i] = Pf[(i >> 6) * 68 + (i & 63)];
  if (wv == 0) {
    float mt = (lane < ke) ? u.m_arr[lane] : 0.0f;
    float msum = wave_sum64(mt);
    if (lane == 0) scales[sid] = msum + lsres;
  }
}

// K2: per-batch scan over 32 segment matrices (wave0 compute, wave1 stage).
__global__ __launch_bounds__(128) void asg_k2(const float* __restrict__ inputs,
                                              char* __restrict__ ws) {
  __shared__ __align__(16) float Gl[2][64][68];
  __shared__ __align__(16) float Eb[64];
  const int tid = threadIdx.x, lane = tid & 63, wv = tid >> 6;
  const int b = blockIdx.x;
  const __bf16* M = (const __bf16*)ws;
  const float* scales = (const float*)(ws + OFF_SCALE);
  float* full = (float*)(ws + OFF_FULL);

  auto stage = [&](int s, int buf) {
    const __bf16* g = M + ((size_t)(b * NSEG + s)) * 4096 + lane * 64;
#pragma unroll
    for (int q = 0; q < 8; ++q) {
      bf16x8 v = *(const bf16x8*)(g + q * 8);
      float4 f0{(float)v[0], (float)v[1], (float)v[2], (float)v[3]};
      float4 f1{(float)v[4], (float)v[5], (float)v[6], (float)v[7]};
      *(float4*)&Gl[buf][lane][q * 8] = f0;
      *(float4*)&Gl[buf][lane][q * 8 + 4] = f1;
    }
  };

  float Ev = 0.0f, ls = 0.0f;
  if (wv == 0) {
    float x0 = inputs[b * L_ + lane];
    float m0 = wave_max64(x0);
    Ev = __expf(x0 - m0);
    ls = m0;
    Eb[lane] = Ev;
  } else {
    stage(0, 0);
  }
  __syncthreads();
  for (int s = 0; s < NSEG; ++s) {
    if (wv == 1 && s + 1 < NSEG) stage(s + 1, (s + 1) & 1);
    if (wv == 0) {
      const int buf = s & 1;
      float ap0 = 0, ap1 = 0, ap2 = 0, ap3 = 0;
#pragma unroll
      for (int k4 = 0; k4 < 16; ++k4) {
        float4 e4 = *(const float4*)&Eb[k4 * 4];
        ap0 = fmaf(Gl[buf][4 * k4 + 0][lane], e4.x, ap0);
        ap1 = fmaf(Gl[buf][4 * k4 + 1][lane], e4.y, ap1);
        ap2 = fmaf(Gl[buf][4 * k4 + 2][lane], e4.z, ap2);
        ap3 = fmaf(Gl[buf][4 * k4 + 3][lane], e4.w, ap3);
      }
      float ap = (ap0 + ap1) + (ap2 + ap3);
      float mx = wave_max64(ap);
      float sc = __builtin_amdgcn_rcpf(mx);
      Ev = ap * sc;
      Eb[lane] = Ev;
      ls += __logf(mx) + scales[b * NSEG + s];
    }
    __syncthreads();
  }
  if (wv == 0) {
    float ssum = wave_sum64(Ev);
    if (lane == 0) full[b] = ls + __logf(ssum);
  }
}

__global__ void asg_k3(const char* __restrict__ ws, float* __restrict__ out) {
  const int j = threadIdx.x;
  const float* full = (const float*)(ws + OFF_FULL);
  const float* alig = (const float*)(ws + OFF_AL);
  float d = full[j] - alig[j];
  d = wave_sum64(d);
  if (j == 0) out[0] = d * (1.0f / 64.0f);
}

extern "C" void kernel_launch(void* const* d_in, const int* in_sizes, int n_in,
                              void* d_out, int out_size, void* d_ws,
                              size_t ws_size, hipStream_t stream) {
  const float* inputs = (const float*)d_in[0];
  const float* trans = (const float*)d_in[1];
  const int* targets = (const int*)d_in[2];
  const int* ilen = (const int*)d_in[3];
  const int* tlen = (const int*)d_in[4];
  char* ws = (char*)d_ws;
  float* out = (float*)d_out;

  hipLaunchKernelGGL(asg_p1, dim3(NSEG * B_), dim3(256), 0, stream,
                     inputs, trans, ilen, ws);
  hipLaunchKernelGGL(asg_fac, dim3(B_), dim3(128), 0, stream,
                     inputs, trans, targets, ilen, tlen, ws);
  hipLaunchKernelGGL(asg_k2, dim3(B_), dim3(128), 0, stream, inputs, ws);
  hipLaunchKernelGGL(asg_k3, dim3(1), dim3(64), 0, stream, ws, out);
}

// Round 7
// 325.207 us; speedup vs baseline: 2.6345x; 1.3263x over previous
//
#include <hip/hip_runtime.h>
#include <math.h>

// ASG loss, MI355X. inputs (T,B,L) f32, trans (L,L) f32, targets (B,S) i32,
// input_lengths (B,) i32, target_lengths (B,) i32. out = mean(full - aligned).
//
// asg_k1 (2112 blocks x 256):
//   blocks 0..63   : fac — exact serial bidiagonal scan, log2 domain.
//     wave0 compute (1 ds_read_b64 + 1 bpermute per step, prefetch-2),
//     wave1 global->E (f16, coalesced), wave2 E->Eg regather (compute layout),
//     wave3 barrier-only.
//   blocks 64..2111: fcc phase 1 — 64-step segment transfer-matrix products
//     on MFMA (exp domain, row-max + lag-8 rescale).
// asg_k2 (64 blocks): per-batch scan over 32 segment matrices + LSE.
// asg_k3: combine. NOTE: needs ~16.8 MB of d_ws.

constexpr int T_ = 2048, B_ = 64, L_ = 64, S_ = 256;
constexpr int CSEG = 64, NSEG = 32;  // fcc segments cover t = 1..2047
constexpr int FCH = 32;              // fac chunk rows
constexpr float NEGV = -1e30f;
constexpr float LOG2E = 1.4426950408889634f;
constexpr float LN2 = 0.6931471805599453f;

typedef __bf16 bf16x8 __attribute__((ext_vector_type(8)));
typedef __bf16 bf16x4 __attribute__((ext_vector_type(4)));
typedef float f32x16 __attribute__((ext_vector_type(16)));
typedef _Float16 f16x4 __attribute__((ext_vector_type(4)));

constexpr size_t OFF_SCALE = (size_t)NSEG * B_ * 4096 * 2;  // 16 MB of M_seg
constexpr size_t OFF_FULL = OFF_SCALE + (size_t)NSEG * B_ * 4;
constexpr size_t OFF_AL = OFF_FULL + (size_t)B_ * 4;

__device__ __forceinline__ float wave_max64(float v) {
#pragma unroll
  for (int off = 1; off < 64; off <<= 1) v = fmaxf(v, __shfl_xor(v, off, 64));
  return v;
}
__device__ __forceinline__ float wave_sum64(float v) {
#pragma unroll
  for (int off = 1; off < 64; off <<= 1) v += __shfl_xor(v, off, 64);
  return v;
}
__device__ __forceinline__ float ex2(float x) {
  return __builtin_amdgcn_exp2f(x);  // raw v_exp_f32
}
__device__ __forceinline__ float lg2(float x) {
  return __builtin_amdgcn_logf(x);   // raw v_log_f32
}
// log2-domain logaddexp of two finite values
__device__ __forceinline__ float lse2(float u, float v) {
  float mx = fmaxf(u, v), mn = fminf(u, v);
  return mx + lg2(1.0f + ex2(mn - mx));
}

struct P1shm {
  __align__(16) float xs[CSEG][64];
  __align__(16) float m_arr[CSEG];
  __align__(16) float redmax[4];
  __align__(16) __bf16 P[2][64 * 68];  // col-major, stride 68
};
struct FACshm {
  __align__(16) _Float16 E[2][FCH][64];    // staged rows (*log2e), 8 KB
  __align__(16) _Float16 Eg[2][FCH][256];  // gathered, compute layout, 32 KB
};
union KU {
  P1shm p1;
  FACshm fac;
};

__global__ __launch_bounds__(256) void asg_k1(
    const float* __restrict__ inputs, const float* __restrict__ trans,
    const int* __restrict__ targets, const int* __restrict__ ilen,
    const int* __restrict__ tlenp, char* __restrict__ ws) {
  __shared__ KU u;
  const int tid = threadIdx.x, lane = tid & 63, wv = tid >> 6;
  const int bid = blockIdx.x;
  float* scales = (float*)(ws + OFF_SCALE);
  float* alig = (float*)(ws + OFF_AL);

  if (bid < B_) {
    // ============================ FAC ============================
    const int b = bid;
    const int len = ilen[b];
    const int tl = tlenp[b];

    // targets for waves 0 (compute) and 2 (regather)
    int tg0 = 0, tg1 = 0, tg2 = 0, tg3 = 0;
    if (wv == 0 || wv == 2) {
      int4 t4 = *(const int4*)(targets + b * S_ + lane * 4);
      tg0 = t4.x; tg1 = t4.y; tg2 = t4.z; tg3 = t4.w;
    }
    float st0 = 0, st1 = 0, st2 = 0, st3 = 0;
    float mt0 = 0, mt1 = 0, mt2 = 0, mt3 = 0;
    if (wv == 0) {
      int tgm1 = (lane > 0) ? targets[b * S_ + lane * 4 - 1] : 0;
      st0 = trans[tg0 * 64 + tg0] * LOG2E;
      st1 = trans[tg1 * 64 + tg1] * LOG2E;
      st2 = trans[tg2 * 64 + tg2] * LOG2E;
      st3 = trans[tg3 * 64 + tg3] * LOG2E;
      mt0 = (lane == 0) ? NEGV : trans[tg0 * 64 + tgm1] * LOG2E;
      mt1 = trans[tg1 * 64 + tg0] * LOG2E;
      mt2 = trans[tg2 * 64 + tg1] * LOG2E;
      mt3 = trans[tg3 * 64 + tg2] * LOG2E;
    }

    auto stage = [&](int c, int buf) {  // wave1: global -> E (f16)
      const float* base = inputs + (size_t)(c * FCH) * (B_ * L_) + b * L_;
#pragma unroll
      for (int i = 0; i < 8; ++i) {
        int f = lane + 64 * i;  // 512 float4 per 32-row chunk
        int r = f >> 4, c4 = f & 15;
        float4 v = *(const float4*)(base + (size_t)r * (B_ * L_) + c4 * 4);
        f16x4 h;
        h[0] = (_Float16)(v.x * LOG2E); h[1] = (_Float16)(v.y * LOG2E);
        h[2] = (_Float16)(v.z * LOG2E); h[3] = (_Float16)(v.w * LOG2E);
        *(f16x4*)&u.fac.E[buf][r][c4 * 4] = h;
      }
    };
    auto regather = [&](int c, int buf) {  // wave2: E -> Eg (compute layout)
#pragma unroll 4
      for (int r = 0; r < FCH; ++r) {
        f16x4 h;
        h[0] = u.fac.E[buf][r][tg0]; h[1] = u.fac.E[buf][r][tg1];
        h[2] = u.fac.E[buf][r][tg2]; h[3] = u.fac.E[buf][r][tg3];
        *(f16x4*)&u.fac.Eg[buf][r][lane * 4] = h;
      }
    };

    if (wv == 1) { stage(0, 0); stage(1, 1); }
    __syncthreads();
    if (wv == 2) regather(0, 0);
    __syncthreads();

    float a0 = NEGV, a1 = NEGV, a2 = NEGV, a3 = NEGV;
    float shv = NEGV;
    const int addr_up = ((lane + 63) & 63) << 2;
    if (wv == 0) a0 = (lane == 0) ? (float)u.fac.Eg[0][0][0] : NEGV;

    for (int c = 0; c * FCH < len; ++c) {
      const int buf = c & 1;
      if (wv == 1) {
        if ((c + 2) * FCH < len) stage(c + 2, buf);
      } else if (wv == 2) {
        if ((c + 1) * FCH < len) regather(c + 1, buf ^ 1);
      } else if (wv == 0) {
        const int r0 = (c == 0) ? 1 : 0;
        const int rmax = min(FCH, len - c * FCH);
        f16x4 eH = *(const f16x4*)&u.fac.Eg[buf][r0][lane * 4];
        f16x4 pH = *(const f16x4*)&u.fac.Eg[buf][min(r0 + 1, rmax - 1)][lane * 4];
        for (int r = r0; r < rmax; ++r) {
          f16x4 nH = *(const f16x4*)&u.fac.Eg[buf][min(r + 2, rmax - 1)][lane * 4];
          float e0 = (float)eH[0], e1 = (float)eH[1];
          float e2 = (float)eH[2], e3 = (float)eH[3];
          // carried chain = this lse only
          float n3 = e3 + lse2(a3 + st3, a2 + mt3);
          float shn = __int_as_float(
              __builtin_amdgcn_ds_bpermute(addr_up, __float_as_int(n3)));
          float n0 = e0 + lse2(a0 + st0, shv + mt0);
          float n1 = e1 + lse2(a1 + st1, a0 + mt1);
          float n2 = e2 + lse2(a2 + st2, a1 + mt2);
          a0 = n0; a1 = n1; a2 = n2; a3 = n3;
          shv = (lane == 0) ? NEGV : shn;  // consumed next step -> off-chain
          eH = pH; pH = nH;
        }
      }
      __syncthreads();
    }
    if (wv == 0) {
      const int idx = tl - 1;
      if ((idx >> 2) == lane) {
        const int r3 = idx & 3;
        float res = (r3 == 0) ? a0 : (r3 == 1) ? a1 : (r3 == 2) ? a2 : a3;
        alig[b] = res * LN2;
      }
    }
    return;
  }

  // ========================= FCC PHASE 1 (MFMA) =========================
  const int sid = bid - B_;
  const int b = sid >> 5, s = sid & 31;
  const int t0 = 1 + s * CSEG;
  const int len = ilen[b];
  int ke = min(CSEG, T_ - t0);
  ke = min(ke, len - t0);
  if (ke < 0) ke = 0;

#pragma unroll
  for (int i = 0; i < 4; ++i) {
    int f4 = tid + 256 * i;
    int r = f4 >> 4, c4 = f4 & 15;
    int t = t0 + r;
    if (t > T_ - 1) t = T_ - 1;
    float4 v = *(const float4*)(inputs + (size_t)t * (B_ * L_) + b * L_ + c4 * 4);
    *(float4*)(&u.p1.xs[r][c4 * 4]) = v;
  }
  __syncthreads();
#pragma unroll
  for (int rr = 0; rr < 16; ++rr) {
    int r = wv * 16 + rr;
    float v = wave_max64(u.p1.xs[r][lane]);
    if (lane == 0) u.p1.m_arr[r] = v;
  }
  __syncthreads();
#pragma unroll
  for (int i = 0; i < 4; ++i) {
    int f4 = tid + 256 * i;
    int r = f4 >> 4, c4 = f4 & 15;
    float m = u.p1.m_arr[r];
    float4 v = *(float4*)(&u.p1.xs[r][c4 * 4]);
    v.x = __expf(v.x - m); v.y = __expf(v.y - m);
    v.z = __expf(v.z - m); v.w = __expf(v.w - m);
    *(float4*)(&u.p1.xs[r][c4 * 4]) = v;
  }
  for (int i = tid; i < 64 * 68; i += 256) u.p1.P[0][i] = (__bf16)0.0f;
  __syncthreads();
  if (tid < 64) u.p1.P[0][tid * 68 + tid] = (__bf16)1.0f;

  const int ma = wv >> 1, nb = wv & 1;
  const int arow = 32 * ma + (lane & 31);
  const int hh = lane >> 5;
  const int coln = 32 * nb + (lane & 31);
  float Wf[4][8];
#pragma unroll
  for (int kc = 0; kc < 4; ++kc) {
    const float* tp = trans + arow * 64 + kc * 16 + hh * 8;
#pragma unroll
    for (int j = 0; j < 8; ++j) Wf[kc][j] = __expf(tp[j]);
  }

  float lsres = 0.0f;
  int cur = 0;
  for (int k = 0; k < ke; ++k) {
    __syncthreads();
    float scf = 1.0f;
    if ((k & 7) == 0 && k != 0) {
      float mm = fmaxf(fmaxf(u.p1.redmax[0], u.p1.redmax[1]),
                       fmaxf(u.p1.redmax[2], u.p1.redmax[3]));
      scf = __builtin_amdgcn_rcpf(mm);
      lsres += __logf(mm);
    }
    const float srow = u.p1.xs[k][arow] * scf;
    bf16x8 A[4], Bf[4];
    const __bf16* Pc = u.p1.P[cur];
#pragma unroll
    for (int kc = 0; kc < 4; ++kc) {
#pragma unroll
      for (int j = 0; j < 8; ++j) A[kc][j] = (__bf16)(Wf[kc][j] * srow);
      const __bf16* p = Pc + coln * 68 + kc * 16 + hh * 8;
      bf16x4 lo = *(const bf16x4*)p;
      bf16x4 hi = *(const bf16x4*)(p + 4);
      Bf[kc] = __builtin_shufflevector(lo, hi, 0, 1, 2, 3, 4, 5, 6, 7);
    }
    f32x16 acc;
#pragma unroll
    for (int e = 0; e < 16; ++e) acc[e] = 0.0f;
    acc = __builtin_amdgcn_mfma_f32_32x32x16_bf16(A[0], Bf[0], acc, 0, 0, 0);
    acc = __builtin_amdgcn_mfma_f32_32x32x16_bf16(A[1], Bf[1], acc, 0, 0, 0);
    acc = __builtin_amdgcn_mfma_f32_32x32x16_bf16(A[2], Bf[2], acc, 0, 0, 0);
    acc = __builtin_amdgcn_mfma_f32_32x32x16_bf16(A[3], Bf[3], acc, 0, 0, 0);
    __bf16* Pn = u.p1.P[cur ^ 1];
#pragma unroll
    for (int q = 0; q < 4; ++q) {
      const int i0 = 32 * ma + 8 * q + 4 * hh;
      bf16x4 w;
      w[0] = (__bf16)acc[4 * q + 0]; w[1] = (__bf16)acc[4 * q + 1];
      w[2] = (__bf16)acc[4 * q + 2]; w[3] = (__bf16)acc[4 * q + 3];
      *(bf16x4*)(Pn + coln * 68 + i0) = w;
    }
    if ((k & 7) == 7) {
      float mx = acc[0];
#pragma unroll
      for (int e = 1; e < 16; ++e) mx = fmaxf(mx, acc[e]);
      mx = wave_max64(mx);
      if (lane == 0) u.p1.redmax[wv] = mx;
    }
    cur ^= 1;
  }
  __syncthreads();
  __bf16* G = ((__bf16*)ws) + (size_t)sid * 4096;
  const __bf16* Pf = u.p1.P[cur];
  for (int i = tid; i < 4096; i += 256) G[i] = Pf[(i >> 6) * 68 + (i & 63)];
  if (wv == 0) {
    float mt = (lane < ke) ? u.p1.m_arr[lane] : 0.0f;
    float msum = wave_sum64(mt);
    if (lane == 0) scales[sid] = msum + lsres;
  }
}

// K2: per-batch scan over 32 segment matrices (wave0 compute, wave1 stage).
__global__ __launch_bounds__(128) void asg_k2(const float* __restrict__ inputs,
                                              char* __restrict__ ws) {
  __shared__ __align__(16) float Gl[2][64][68];
  __shared__ __align__(16) float Eb[64];
  const int tid = threadIdx.x, lane = tid & 63, wv = tid >> 6;
  const int b = blockIdx.x;
  const __bf16* M = (const __bf16*)ws;
  const float* scales = (const float*)(ws + OFF_SCALE);
  float* full = (float*)(ws + OFF_FULL);

  auto stage = [&](int s, int buf) {
    const __bf16* g = M + ((size_t)(b * NSEG + s)) * 4096 + lane * 64;
#pragma unroll
    for (int q = 0; q < 8; ++q) {
      bf16x8 v = *(const bf16x8*)(g + q * 8);
      float4 f0{(float)v[0], (float)v[1], (float)v[2], (float)v[3]};
      float4 f1{(float)v[4], (float)v[5], (float)v[6], (float)v[7]};
      *(float4*)&Gl[buf][lane][q * 8] = f0;
      *(float4*)&Gl[buf][lane][q * 8 + 4] = f1;
    }
  };

  float Ev = 0.0f, ls = 0.0f;
  if (wv == 0) {
    float x0 = inputs[b * L_ + lane];
    float m0 = wave_max64(x0);
    Ev = __expf(x0 - m0);
    ls = m0;
    Eb[lane] = Ev;
  } else {
    stage(0, 0);
  }
  __syncthreads();
  for (int s = 0; s < NSEG; ++s) {
    if (wv == 1 && s + 1 < NSEG) stage(s + 1, (s + 1) & 1);
    if (wv == 0) {
      const int buf = s & 1;
      float ap0 = 0, ap1 = 0, ap2 = 0, ap3 = 0;
#pragma unroll
      for (int k4 = 0; k4 < 16; ++k4) {
        float4 e4 = *(const float4*)&Eb[k4 * 4];
        ap0 = fmaf(Gl[buf][4 * k4 + 0][lane], e4.x, ap0);
        ap1 = fmaf(Gl[buf][4 * k4 + 1][lane], e4.y, ap1);
        ap2 = fmaf(Gl[buf][4 * k4 + 2][lane], e4.z, ap2);
        ap3 = fmaf(Gl[buf][4 * k4 + 3][lane], e4.w, ap3);
      }
      float ap = (ap0 + ap1) + (ap2 + ap3);
      float mx = wave_max64(ap);
      float sc = __builtin_amdgcn_rcpf(mx);
      Ev = ap * sc;
      Eb[lane] = Ev;
      ls += __logf(mx) + scales[b * NSEG + s];
    }
    __syncthreads();
  }
  if (wv == 0) {
    float ssum = wave_sum64(Ev);
    if (lane == 0) full[b] = ls + __logf(ssum);
  }
}

__global__ void asg_k3(const char* __restrict__ ws, float* __restrict__ out) {
  const int j = threadIdx.x;
  const float* full = (const float*)(ws + OFF_FULL);
  const float* alig = (const float*)(ws + OFF_AL);
  float d = full[j] - alig[j];
  d = wave_sum64(d);
  if (j == 0) out[0] = d * (1.0f / 64.0f);
}

extern "C" void kernel_launch(void* const* d_in, const int* in_sizes, int n_in,
                              void* d_out, int out_size, void* d_ws,
                              size_t ws_size, hipStream_t stream) {
  const float* inputs = (const float*)d_in[0];
  const float* trans = (const float*)d_in[1];
  const int* targets = (const int*)d_in[2];
  const int* ilen = (const int*)d_in[3];
  const int* tlen = (const int*)d_in[4];
  char* ws = (char*)d_ws;
  float* out = (float*)d_out;

  hipLaunchKernelGGL(asg_k1, dim3(B_ + NSEG * B_), dim3(256), 0, stream,
                     inputs, trans, targets, ilen, tlen, ws);
  hipLaunchKernelGGL(asg_k2, dim3(B_), dim3(128), 0, stream, inputs, ws);
  hipLaunchKernelGGL(asg_k3, dim3(1), dim3(64), 0, stream, ws, out);
}

// Round 8
// 304.276 us; speedup vs baseline: 2.8157x; 1.0688x over previous
//
#include <hip/hip_runtime.h>
#include <math.h>

// ASG loss, MI355X. inputs (T,B,L) f32, trans (L,L) f32, targets (B,S) i32,
// input_lengths (B,) i32, target_lengths (B,) i32. out = mean(full - aligned).
//
// asg_k1 (2112 blocks x 256):
//   blocks 0..63   : fac — exact serial bidiagonal scan in EXP domain, f64
//     states, power-of-2 rescale every 16-step chunk (exact), emissions
//     staged as f32 exp(x - rowmax). wave0 compute (12 f64 ops/step, no
//     transcendentals), wave1 global->E + rowmax, wave2 E->Eg regather.
//   blocks 64..2111: fcc phase 1 — 64-step segment transfer-matrix products
//     on MFMA (exp domain, row-max + lag-8 rescale).
// asg_k2 (64 blocks): per-batch scan over 32 segment matrices + LSE.
// asg_k3: combine. NOTE: needs ~16.8 MB of d_ws.

constexpr int T_ = 2048, B_ = 64, L_ = 64, S_ = 256;
constexpr int CSEG = 64, NSEG = 32;  // fcc segments cover t = 1..2047
constexpr int FCH = 16;              // fac chunk rows
constexpr float NEGV = -1e30f;
constexpr float LN2 = 0.6931471805599453f;

typedef __bf16 bf16x8 __attribute__((ext_vector_type(8)));
typedef __bf16 bf16x4 __attribute__((ext_vector_type(4)));
typedef float f32x16 __attribute__((ext_vector_type(16)));

constexpr size_t OFF_SCALE = (size_t)NSEG * B_ * 4096 * 2;  // 16 MB of M_seg
constexpr size_t OFF_FULL = OFF_SCALE + (size_t)NSEG * B_ * 4;
constexpr size_t OFF_AL = OFF_FULL + (size_t)B_ * 4;

__device__ __forceinline__ float wave_max64(float v) {
#pragma unroll
  for (int off = 1; off < 64; off <<= 1) v = fmaxf(v, __shfl_xor(v, off, 64));
  return v;
}
__device__ __forceinline__ float wave_sum64(float v) {
#pragma unroll
  for (int off = 1; off < 64; off <<= 1) v += __shfl_xor(v, off, 64);
  return v;
}

struct P1shm {
  __align__(16) float xs[CSEG][64];
  __align__(16) float m_arr[CSEG];
  __align__(16) float redmax[4];
  __align__(16) __bf16 P[2][64 * 68];  // col-major, stride 68
};
struct FACshm {
  __align__(16) float E[2][FCH][64];    // exp(x - m_row), 8 KB
  __align__(16) float Eg[2][FCH][256];  // gathered, compute layout, 32 KB
  __align__(16) float m_fac[2][FCH];    // row maxes
};
union KU {
  P1shm p1;
  FACshm fac;
};

__global__ __launch_bounds__(256) void asg_k1(
    const float* __restrict__ inputs, const float* __restrict__ trans,
    const int* __restrict__ targets, const int* __restrict__ ilen,
    const int* __restrict__ tlenp, char* __restrict__ ws) {
  __shared__ KU u;
  const int tid = threadIdx.x, lane = tid & 63, wv = tid >> 6;
  const int bid = blockIdx.x;
  float* scales = (float*)(ws + OFF_SCALE);
  float* alig = (float*)(ws + OFF_AL);

  if (bid < B_) {
    // ================== FAC (exp domain, f64 states) ==================
    const int b = bid;
    const int len = ilen[b];
    const int tl = tlenp[b];

    int tg0 = 0, tg1 = 0, tg2 = 0, tg3 = 0;
    if (wv == 0 || wv == 2) {
      int4 t4 = *(const int4*)(targets + b * S_ + lane * 4);
      tg0 = t4.x; tg1 = t4.y; tg2 = t4.z; tg3 = t4.w;
    }
    double sw0 = 0, sw1 = 0, sw2 = 0, sw3 = 0;
    double mw0 = 0, mw1 = 0, mw2 = 0, mw3 = 0;
    if (wv == 0) {
      int tgm1 = (lane > 0) ? targets[b * S_ + lane * 4 - 1] : 0;
      sw0 = exp((double)trans[tg0 * 64 + tg0]);
      sw1 = exp((double)trans[tg1 * 64 + tg1]);
      sw2 = exp((double)trans[tg2 * 64 + tg2]);
      sw3 = exp((double)trans[tg3 * 64 + tg3]);
      mw0 = (lane == 0) ? 0.0 : exp((double)trans[tg0 * 64 + tgm1]);
      mw1 = exp((double)trans[tg1 * 64 + tg0]);
      mw2 = exp((double)trans[tg2 * 64 + tg1]);
      mw3 = exp((double)trans[tg3 * 64 + tg2]);
    }

    auto stage = [&](int c, int buf) {  // wave1: global -> E, rowmax
#pragma unroll
      for (int i = 0; i < 4; ++i) {
        int f = lane + 64 * i;  // 256 float4 per 16-row chunk
        int r = f >> 4, c4 = f & 15;
        int t = c * FCH + r;
        if (t > T_ - 1) t = T_ - 1;  // clamp (never consumed past len)
        float4 v = *(const float4*)(inputs + (size_t)t * (B_ * L_) + b * L_ +
                                    c4 * 4);
        float m = fmaxf(fmaxf(v.x, v.y), fmaxf(v.z, v.w));
#pragma unroll
        for (int off = 1; off < 16; off <<= 1)
          m = fmaxf(m, __shfl_xor(m, off, 64));  // max within 16-lane row grp
        v.x = __expf(v.x - m); v.y = __expf(v.y - m);
        v.z = __expf(v.z - m); v.w = __expf(v.w - m);
        *(float4*)&u.fac.E[buf][r][c4 * 4] = v;
        if ((lane & 15) == 0) u.fac.m_fac[buf][r] = m;
      }
    };
    auto regather = [&](int c, int buf) {  // wave2: E -> Eg (compute layout)
#pragma unroll 4
      for (int r = 0; r < FCH; ++r) {
        float4 h;
        h.x = u.fac.E[buf][r][tg0]; h.y = u.fac.E[buf][r][tg1];
        h.z = u.fac.E[buf][r][tg2]; h.w = u.fac.E[buf][r][tg3];
        *(float4*)&u.fac.Eg[buf][r][lane * 4] = h;
      }
    };

    if (wv == 1) { stage(0, 0); stage(1, 1); }
    __syncthreads();
    if (wv == 2) regather(0, 0);
    __syncthreads();

    double d0 = 0.0, d1 = 0.0, d2 = 0.0, d3 = 0.0, shv = 0.0;
    float Lacc = 0.0f;
    const int addr_up = ((lane + 63) & 63) << 2;
    if (wv == 0) {
      if (lane == 0) d0 = (double)u.fac.Eg[0][0][0];
      Lacc = u.fac.m_fac[0][0];
    }

    for (int c = 0; c * FCH < len; ++c) {
      const int buf = c & 1;
      if (wv == 1) {
        if ((c + 2) * FCH < len) stage(c + 2, buf);
      } else if (wv == 2) {
        if ((c + 1) * FCH < len) regather(c + 1, buf ^ 1);
      } else if (wv == 0) {
        if (c) {  // exact power-of-2 rescale to the wave max
          double dmax = fmax(fmax(d0, d1), fmax(d2, d3));
#pragma unroll
          for (int off = 1; off < 64; off <<= 1)
            dmax = fmax(dmax, __shfl_xor(dmax, off, 64));
          long long lm = __double_as_longlong(dmax);
          int ex = (int)((lm >> 52) & 0x7FF);
          double M = __longlong_as_double((long long)(2046 - ex) << 52);
          d0 *= M; d1 *= M; d2 *= M; d3 *= M; shv *= M;
          Lacc += (float)(ex - 1023) * LN2;
        }
        const int r0 = (c == 0) ? 1 : 0;
        const int rmax = min(FCH, len - c * FCH);
        float4 eH = *(const float4*)&u.fac.Eg[buf][r0][lane * 4];
        float mH = u.fac.m_fac[buf][r0];
        const int r1 = min(r0 + 1, FCH - 1);
        float4 pH = *(const float4*)&u.fac.Eg[buf][r1][lane * 4];
        float pM = u.fac.m_fac[buf][r1];
        for (int r = r0; r < rmax; ++r) {
          const int rn = min(r + 2, FCH - 1);
          float4 nH = *(const float4*)&u.fac.Eg[buf][rn][lane * 4];
          float nM = u.fac.m_fac[buf][rn];
          // carried chain: mul+fma+mul (f64), no transcendentals
          double nd3 = (double)eH.w * fma(mw3, d2, sw3 * d3);
          long long l3 = __double_as_longlong(nd3);
          int slo = __builtin_amdgcn_ds_bpermute(addr_up, (int)l3);
          int shi = __builtin_amdgcn_ds_bpermute(addr_up, (int)(l3 >> 32));
          double nd0 = (double)eH.x * fma(mw0, shv, sw0 * d0);
          double nd1 = (double)eH.y * fma(mw1, d0, sw1 * d1);
          double nd2 = (double)eH.z * fma(mw2, d1, sw2 * d2);
          d0 = nd0; d1 = nd1; d2 = nd2; d3 = nd3;
          double sh = __longlong_as_double(((long long)shi << 32) |
                                           (unsigned int)slo);
          shv = (lane == 0) ? 0.0 : sh;  // consumed next step -> off-chain
          Lacc += mH;
          eH = pH; mH = pM; pH = nH; pM = nM;
        }
      }
      __syncthreads();
    }
    if (wv == 0) {
      const int idx = tl - 1;
      if ((idx >> 2) == lane) {
        const int r3 = idx & 3;
        double dv = (r3 == 0) ? d0 : (r3 == 1) ? d1 : (r3 == 2) ? d2 : d3;
        long long ld = __double_as_longlong(dv);
        int ex = (int)((ld >> 52) & 0x7FF);
        double mant = __longlong_as_double((ld & 0xFFFFFFFFFFFFFLL) |
                                           (1023LL << 52));
        alig[b] = Lacc + (float)(ex - 1023) * LN2 + __logf((float)mant);
      }
    }
    return;
  }

  // ========================= FCC PHASE 1 (MFMA) =========================
  const int sid = bid - B_;
  const int b = sid >> 5, s = sid & 31;
  const int t0 = 1 + s * CSEG;
  const int len = ilen[b];
  int ke = min(CSEG, T_ - t0);
  ke = min(ke, len - t0);
  if (ke < 0) ke = 0;

#pragma unroll
  for (int i = 0; i < 4; ++i) {
    int f4 = tid + 256 * i;
    int r = f4 >> 4, c4 = f4 & 15;
    int t = t0 + r;
    if (t > T_ - 1) t = T_ - 1;
    float4 v = *(const float4*)(inputs + (size_t)t * (B_ * L_) + b * L_ + c4 * 4);
    *(float4*)(&u.p1.xs[r][c4 * 4]) = v;
  }
  __syncthreads();
#pragma unroll
  for (int rr = 0; rr < 16; ++rr) {
    int r = wv * 16 + rr;
    float v = wave_max64(u.p1.xs[r][lane]);
    if (lane == 0) u.p1.m_arr[r] = v;
  }
  __syncthreads();
#pragma unroll
  for (int i = 0; i < 4; ++i) {
    int f4 = tid + 256 * i;
    int r = f4 >> 4, c4 = f4 & 15;
    float m = u.p1.m_arr[r];
    float4 v = *(float4*)(&u.p1.xs[r][c4 * 4]);
    v.x = __expf(v.x - m); v.y = __expf(v.y - m);
    v.z = __expf(v.z - m); v.w = __expf(v.w - m);
    *(float4*)(&u.p1.xs[r][c4 * 4]) = v;
  }
  for (int i = tid; i < 64 * 68; i += 256) u.p1.P[0][i] = (__bf16)0.0f;
  __syncthreads();
  if (tid < 64) u.p1.P[0][tid * 68 + tid] = (__bf16)1.0f;

  const int ma = wv >> 1, nb = wv & 1;
  const int arow = 32 * ma + (lane & 31);
  const int hh = lane >> 5;
  const int coln = 32 * nb + (lane & 31);
  float Wf[4][8];
#pragma unroll
  for (int kc = 0; kc < 4; ++kc) {
    const float* tp = trans + arow * 64 + kc * 16 + hh * 8;
#pragma unroll
    for (int j = 0; j < 8; ++j) Wf[kc][j] = __expf(tp[j]);
  }

  float lsres = 0.0f;
  int cur = 0;
  for (int k = 0; k < ke; ++k) {
    __syncthreads();
    float scf = 1.0f;
    if ((k & 7) == 0 && k != 0) {
      float mm = fmaxf(fmaxf(u.p1.redmax[0], u.p1.redmax[1]),
                       fmaxf(u.p1.redmax[2], u.p1.redmax[3]));
      scf = __builtin_amdgcn_rcpf(mm);
      lsres += __logf(mm);
    }
    const float srow = u.p1.xs[k][arow] * scf;
    bf16x8 A[4], Bf[4];
    const __bf16* Pc = u.p1.P[cur];
#pragma unroll
    for (int kc = 0; kc < 4; ++kc) {
#pragma unroll
      for (int j = 0; j < 8; ++j) A[kc][j] = (__bf16)(Wf[kc][j] * srow);
      const __bf16* p = Pc + coln * 68 + kc * 16 + hh * 8;
      bf16x4 lo = *(const bf16x4*)p;
      bf16x4 hi = *(const bf16x4*)(p + 4);
      Bf[kc] = __builtin_shufflevector(lo, hi, 0, 1, 2, 3, 4, 5, 6, 7);
    }
    f32x16 acc;
#pragma unroll
    for (int e = 0; e < 16; ++e) acc[e] = 0.0f;
    acc = __builtin_amdgcn_mfma_f32_32x32x16_bf16(A[0], Bf[0], acc, 0, 0, 0);
    acc = __builtin_amdgcn_mfma_f32_32x32x16_bf16(A[1], Bf[1], acc, 0, 0, 0);
    acc = __builtin_amdgcn_mfma_f32_32x32x16_bf16(A[2], Bf[2], acc, 0, 0, 0);
    acc = __builtin_amdgcn_mfma_f32_32x32x16_bf16(A[3], Bf[3], acc, 0, 0, 0);
    __bf16* Pn = u.p1.P[cur ^ 1];
#pragma unroll
    for (int q = 0; q < 4; ++q) {
      const int i0 = 32 * ma + 8 * q + 4 * hh;
      bf16x4 w;
      w[0] = (__bf16)acc[4 * q + 0]; w[1] = (__bf16)acc[4 * q + 1];
      w[2] = (__bf16)acc[4 * q + 2]; w[3] = (__bf16)acc[4 * q + 3];
      *(bf16x4*)(Pn + coln * 68 + i0) = w;
    }
    if ((k & 7) == 7) {
      float mx = acc[0];
#pragma unroll
      for (int e = 1; e < 16; ++e) mx = fmaxf(mx, acc[e]);
      mx = wave_max64(mx);
      if (lane == 0) u.p1.redmax[wv] = mx;
    }
    cur ^= 1;
  }
  __syncthreads();
  __bf16* G = ((__bf16*)ws) + (size_t)sid * 4096;
  const __bf16* Pf = u.p1.P[cur];
  for (int i = tid; i < 4096; i += 256) G[i] = Pf[(i >> 6) * 68 + (i & 63)];
  if (wv == 0) {
    float mt = (lane < ke) ? u.p1.m_arr[lane] : 0.0f;
    float msum = wave_sum64(mt);
    if (lane == 0) scales[sid] = msum + lsres;
  }
}

// K2: per-batch scan over 32 segment matrices (wave0 compute, wave1 stage).
__global__ __launch_bounds__(128) void asg_k2(const float* __restrict__ inputs,
                                              char* __restrict__ ws) {
  __shared__ __align__(16) float Gl[2][64][68];
  __shared__ __align__(16) float Eb[64];
  const int tid = threadIdx.x, lane = tid & 63, wv = tid >> 6;
  const int b = blockIdx.x;
  const __bf16* M = (const __bf16*)ws;
  const float* scales = (const float*)(ws + OFF_SCALE);
  float* full = (float*)(ws + OFF_FULL);

  auto stage = [&](int s, int buf) {
    const __bf16* g = M + ((size_t)(b * NSEG + s)) * 4096 + lane * 64;
#pragma unroll
    for (int q = 0; q < 8; ++q) {
      bf16x8 v = *(const bf16x8*)(g + q * 8);
      float4 f0{(float)v[0], (float)v[1], (float)v[2], (float)v[3]};
      float4 f1{(float)v[4], (float)v[5], (float)v[6], (float)v[7]};
      *(float4*)&Gl[buf][lane][q * 8] = f0;
      *(float4*)&Gl[buf][lane][q * 8 + 4] = f1;
    }
  };

  float Ev = 0.0f, ls = 0.0f;
  if (wv == 0) {
    float x0 = inputs[b * L_ + lane];
    float m0 = wave_max64(x0);
    Ev = __expf(x0 - m0);
    ls = m0;
    Eb[lane] = Ev;
  } else {
    stage(0, 0);
  }
  __syncthreads();
  for (int s = 0; s < NSEG; ++s) {
    if (wv == 1 && s + 1 < NSEG) stage(s + 1, (s + 1) & 1);
    if (wv == 0) {
      const int buf = s & 1;
      float ap0 = 0, ap1 = 0, ap2 = 0, ap3 = 0;
#pragma unroll
      for (int k4 = 0; k4 < 16; ++k4) {
        float4 e4 = *(const float4*)&Eb[k4 * 4];
        ap0 = fmaf(Gl[buf][4 * k4 + 0][lane], e4.x, ap0);
        ap1 = fmaf(Gl[buf][4 * k4 + 1][lane], e4.y, ap1);
        ap2 = fmaf(Gl[buf][4 * k4 + 2][lane], e4.z, ap2);
        ap3 = fmaf(Gl[buf][4 * k4 + 3][lane], e4.w, ap3);
      }
      float ap = (ap0 + ap1) + (ap2 + ap3);
      float mx = wave_max64(ap);
      float sc = __builtin_amdgcn_rcpf(mx);
      Ev = ap * sc;
      Eb[lane] = Ev;
      ls += __logf(mx) + scales[b * NSEG + s];
    }
    __syncthreads();
  }
  if (wv == 0) {
    float ssum = wave_sum64(Ev);
    if (lane == 0) full[b] = ls + __logf(ssum);
  }
}

__global__ void asg_k3(const char* __restrict__ ws, float* __restrict__ out) {
  const int j = threadIdx.x;
  const float* full = (const float*)(ws + OFF_FULL);
  const float* alig = (const float*)(ws + OFF_AL);
  float d = full[j] - alig[j];
  d = wave_sum64(d);
  if (j == 0) out[0] = d * (1.0f / 64.0f);
}

extern "C" void kernel_launch(void* const* d_in, const int* in_sizes, int n_in,
                              void* d_out, int out_size, void* d_ws,
                              size_t ws_size, hipStream_t stream) {
  const float* inputs = (const float*)d_in[0];
  const float* trans = (const float*)d_in[1];
  const int* targets = (const int*)d_in[2];
  const int* ilen = (const int*)d_in[3];
  const int* tlen = (const int*)d_in[4];
  char* ws = (char*)d_ws;
  float* out = (float*)d_out;

  hipLaunchKernelGGL(asg_k1, dim3(B_ + NSEG * B_), dim3(256), 0, stream,
                     inputs, trans, targets, ilen, tlen, ws);
  hipLaunchKernelGGL(asg_k2, dim3(B_), dim3(128), 0, stream, inputs, ws);
  hipLaunchKernelGGL(asg_k3, dim3(1), dim3(64), 0, stream, ws, out);
}

// Round 9
// 197.453 us; speedup vs baseline: 4.3390x; 1.5410x over previous
//
#include <hip/hip_runtime.h>
#include <math.h>

// ASG loss, MI355X. inputs (T,B,L) f32, trans (L,L) f32, targets (B,S) i32,
// input_lengths (B,) i32, target_lengths (B,) i32. out = mean(full - aligned).
//
// asg_k1 (2176 blocks x 256):
//   blocks 0..63    : fac FORWARD chain, t = 1..TS (exp domain, f64 states)
//   blocks 64..127  : fac BACKWARD chain, t = len-1..TS+1 (transposed recur.)
//   blocks 128..2175: fcc phase 1 — 64-step segment transfer-matrix products
//     on MFMA (exp domain, row-max + lag-8 rescale).
//   fac waves: wv0 compute (setprio 1), wv1 stage global->E + rowmax,
//   wv2 regather E->Eg (compute layout) + copy rowmax m_fac->mg (race-free
//   parity: stage writes [buf], regather reads [buf^1], compute reads mg[buf]).
// asg_k2 (64 blocks): per-batch scan over 32 segment matrices + LSE.
// asg_k3 (1 block): per-batch dot(fwd,bwd) in f64 + log + mean combine.
// NOTE: needs ~17.1 MB of d_ws.

constexpr int T_ = 2048, B_ = 64, L_ = 64, S_ = 256;
constexpr int CSEG = 64, NSEG = 32;  // fcc segments cover t = 1..2047
constexpr int FCH = 16;              // fac chunk rows
constexpr float LN2 = 0.6931471805599453f;

typedef __bf16 bf16x8 __attribute__((ext_vector_type(8)));
typedef __bf16 bf16x4 __attribute__((ext_vector_type(4)));
typedef float f32x16 __attribute__((ext_vector_type(16)));

constexpr size_t OFF_SCALE = (size_t)NSEG * B_ * 4096 * 2;  // 16 MB M_seg
constexpr size_t OFF_FULL = OFF_SCALE + (size_t)NSEG * B_ * 4;
constexpr size_t OFF_FWD = OFF_FULL + B_ * 4;
constexpr size_t OFF_BWD = OFF_FWD + (size_t)B_ * 256 * 8;
constexpr size_t OFF_LF = OFF_BWD + (size_t)B_ * 256 * 8;
constexpr size_t OFF_LB = OFF_LF + B_ * 4;

__device__ __forceinline__ float wave_max64(float v) {
#pragma unroll
  for (int off = 1; off < 64; off <<= 1) v = fmaxf(v, __shfl_xor(v, off, 64));
  return v;
}
__device__ __forceinline__ float wave_sum64(float v) {
#pragma unroll
  for (int off = 1; off < 64; off <<= 1) v += __shfl_xor(v, off, 64);
  return v;
}
__device__ __forceinline__ double wave_max64d(double v) {
#pragma unroll
  for (int off = 1; off < 64; off <<= 1) v = fmax(v, __shfl_xor(v, off, 64));
  return v;
}

struct P1shm {
  __align__(16) float xs[CSEG][64];
  __align__(16) float m_arr[CSEG];
  __align__(16) float redmax[4];
  __align__(16) __bf16 P[2][64 * 68];  // col-major, stride 68
};
struct FACshm {
  __align__(16) float E[2][FCH][64];    // exp(x - m_row), 8 KB
  __align__(16) float Eg[2][FCH][256];  // gathered, compute layout, 32 KB
  __align__(16) float m_fac[2][FCH];    // row maxes (stage-side)
  __align__(16) float mg[2][FCH];       // row maxes (compute-side copy)
};
union KU {
  P1shm p1;
  FACshm fac;
};

__global__ __launch_bounds__(256) void asg_k1(
    const float* __restrict__ inputs, const float* __restrict__ trans,
    const int* __restrict__ targets, const int* __restrict__ ilen,
    const int* __restrict__ tlenp, char* __restrict__ ws) {
  __shared__ KU u;
  const int tid = threadIdx.x, lane = tid & 63, wv = tid >> 6;
  const int bid = blockIdx.x;
  float* scales = (float*)(ws + OFF_SCALE);

  if (bid < 2 * B_) {
    // ================== FAC half-chains (exp domain, f64) ==================
    const bool isfwd = (bid < B_);
    const int b = bid & 63;
    const int len = ilen[b];
    const int tl = tlenp[b];
    const int TS = (len - 1) >> 1;
    double* vecout = (double*)(ws + (isfwd ? OFF_FWD : OFF_BWD)) + b * 256;
    float* Lout = (float*)(ws + (isfwd ? OFF_LF : OFF_LB));

    int tg0 = 0, tg1 = 0, tg2 = 0, tg3 = 0;
    if (wv == 0 || wv == 2) {
      int4 t4 = *(const int4*)(targets + b * S_ + lane * 4);
      tg0 = t4.x; tg1 = t4.y; tg2 = t4.z; tg3 = t4.w;
    }
    auto stage = [&](int c, int buf) {  // wave1
#pragma unroll
      for (int i = 0; i < 4; ++i) {
        int f = lane + 64 * i;
        int r = f >> 4, c4 = f & 15;
        int t = c * FCH + r;
        if (t > T_ - 1) t = T_ - 1;
        float4 v = *(const float4*)(inputs + (size_t)t * (B_ * L_) + b * L_ +
                                    c4 * 4);
        float m = fmaxf(fmaxf(v.x, v.y), fmaxf(v.z, v.w));
#pragma unroll
        for (int off = 1; off < 16; off <<= 1)
          m = fmaxf(m, __shfl_xor(m, off, 64));
        v.x = __expf(v.x - m); v.y = __expf(v.y - m);
        v.z = __expf(v.z - m); v.w = __expf(v.w - m);
        *(float4*)&u.fac.E[buf][r][c4 * 4] = v;
        if ((lane & 15) == 0) u.fac.m_fac[buf][r] = m;
      }
    };
    auto regather = [&](int c, int buf) {  // wave2
#pragma unroll 4
      for (int r = 0; r < FCH; ++r) {
        float4 h;
        h.x = u.fac.E[buf][r][tg0]; h.y = u.fac.E[buf][r][tg1];
        h.z = u.fac.E[buf][r][tg2]; h.w = u.fac.E[buf][r][tg3];
        *(float4*)&u.fac.Eg[buf][r][lane * 4] = h;
      }
      if (lane < FCH) u.fac.mg[buf][lane] = u.fac.m_fac[buf][lane];
    };

    if (isfwd) {
      // ---------------- FORWARD: t = 1..TS ----------------
      double sw0 = 0, sw1 = 0, sw2 = 0, sw3 = 0;
      double mw0 = 0, mw1 = 0, mw2 = 0, mw3 = 0;
      if (wv == 0) {
        int tgm1 = (lane > 0) ? targets[b * S_ + lane * 4 - 1] : 0;
        sw0 = exp((double)trans[tg0 * 64 + tg0]);
        sw1 = exp((double)trans[tg1 * 64 + tg1]);
        sw2 = exp((double)trans[tg2 * 64 + tg2]);
        sw3 = exp((double)trans[tg3 * 64 + tg3]);
        mw0 = (lane == 0) ? 0.0 : exp((double)trans[tg0 * 64 + tgm1]);
        mw1 = exp((double)trans[tg1 * 64 + tg0]);
        mw2 = exp((double)trans[tg2 * 64 + tg1]);
        mw3 = exp((double)trans[tg3 * 64 + tg2]);
      }
      if (wv == 1) { stage(0, 0); stage(1, 1); }
      __syncthreads();
      if (wv == 2) regather(0, 0);
      __syncthreads();

      double d0 = 0.0, d1 = 0.0, d2 = 0.0, d3 = 0.0, shv = 0.0;
      float Lacc = 0.0f;
      const int addr_up = ((lane + 63) & 63) << 2;
      if (wv == 0) {
        if (lane == 0) d0 = (double)u.fac.Eg[0][0][0];
        Lacc = u.fac.mg[0][0];
        __builtin_amdgcn_s_setprio(1);
      }
      for (int c = 0; 16 * c <= TS; ++c) {
        const int buf = c & 1;
        if (wv == 1) {
          if (16 * (c + 2) <= TS) stage(c + 2, buf);
        } else if (wv == 2) {
          if (16 * (c + 1) <= TS) regather(c + 1, buf ^ 1);
        } else if (wv == 0) {
          if (c) {  // exact power-of-2 rescale
            double dmax = wave_max64d(fmax(fmax(d0, d1), fmax(d2, d3)));
            long long lm = __double_as_longlong(dmax);
            int ex = (int)((lm >> 52) & 0x7FF);
            double M = __longlong_as_double((long long)(2046 - ex) << 52);
            d0 *= M; d1 *= M; d2 *= M; d3 *= M; shv *= M;
            Lacc += (float)(ex - 1023) * LN2;
          }
          const int r0 = (c == 0) ? 1 : 0;
          const int rmax = min(FCH, TS + 1 - 16 * c);
          float4 eH = *(const float4*)&u.fac.Eg[buf][r0][lane * 4];
          float mH = u.fac.mg[buf][r0];
          const int r1 = min(r0 + 1, FCH - 1);
          float4 pH = *(const float4*)&u.fac.Eg[buf][r1][lane * 4];
          float pM = u.fac.mg[buf][r1];
          for (int r = r0; r < rmax; ++r) {
            const int rn = min(r + 2, FCH - 1);
            float4 nH = *(const float4*)&u.fac.Eg[buf][rn][lane * 4];
            float nM = u.fac.mg[buf][rn];
            double nd3 = (double)eH.w * fma(mw3, d2, sw3 * d3);
            long long l3 = __double_as_longlong(nd3);
            int slo = __builtin_amdgcn_ds_bpermute(addr_up, (int)l3);
            int shi = __builtin_amdgcn_ds_bpermute(addr_up, (int)(l3 >> 32));
            double nd0 = (double)eH.x * fma(mw0, shv, sw0 * d0);
            double nd1 = (double)eH.y * fma(mw1, d0, sw1 * d1);
            double nd2 = (double)eH.z * fma(mw2, d1, sw2 * d2);
            d0 = nd0; d1 = nd1; d2 = nd2; d3 = nd3;
            shv = __longlong_as_double(((long long)shi << 32) |
                                       (unsigned int)slo);
            Lacc += mH;
            eH = pH; mH = pM; pH = nH; pM = nM;
          }
        }
        __syncthreads();
      }
      if (wv == 0) {
        __builtin_amdgcn_s_setprio(0);
        vecout[lane * 4 + 0] = d0; vecout[lane * 4 + 1] = d1;
        vecout[lane * 4 + 2] = d2; vecout[lane * 4 + 3] = d3;
        if (lane == 0) Lout[b] = Lacc;
      }
    } else {
      // ---------------- BACKWARD: t = len-1..TS+1 (transposed) ----------
      double sw0 = 0, sw1 = 0, sw2 = 0, sw3 = 0;
      double mv0 = 0, mv1 = 0, mv2 = 0, mv3 = 0;
      if (wv == 0) {
        int tg4 = (lane < 63) ? targets[b * S_ + lane * 4 + 4] : 0;
        sw0 = exp((double)trans[tg0 * 64 + tg0]);
        sw1 = exp((double)trans[tg1 * 64 + tg1]);
        sw2 = exp((double)trans[tg2 * 64 + tg2]);
        sw3 = exp((double)trans[tg3 * 64 + tg3]);
        mv0 = exp((double)trans[tg1 * 64 + tg0]);   // move[4l+1]
        mv1 = exp((double)trans[tg2 * 64 + tg1]);   // move[4l+2]
        mv2 = exp((double)trans[tg3 * 64 + tg2]);   // move[4l+3]
        mv3 = (lane < 63) ? exp((double)trans[tg4 * 64 + tg3]) : 0.0;
      }
      const int cmax = (len - 1) >> 4;
      const int cmin = (TS + 1) >> 4;
      if (wv == 1) {
        stage(cmax, cmax & 1);
        if (cmax - 1 >= cmin) stage(cmax - 1, (cmax - 1) & 1);
      }
      __syncthreads();
      if (wv == 2) regather(cmax, cmax & 1);
      __syncthreads();

      const int idx = tl - 1;
      double b0 = 0, b1 = 0, b2 = 0, b3 = 0, g0cur = 0, shg = 0;
      float Lacc = 0.0f;
      const int addr_dn = ((lane + 1) & 63) << 2;
      if (wv == 0) {
        b0 = (lane * 4 + 0 == idx) ? 1.0 : 0.0;
        b1 = (lane * 4 + 1 == idx) ? 1.0 : 0.0;
        b2 = (lane * 4 + 2 == idx) ? 1.0 : 0.0;
        b3 = (lane * 4 + 3 == idx) ? 1.0 : 0.0;
        const int rh0 = (len - 1) & 15;
        float e0x = u.fac.Eg[cmax & 1][rh0][lane * 4];
        g0cur = (double)e0x * b0;
        long long lg = __double_as_longlong(g0cur);
        int slo = __builtin_amdgcn_ds_bpermute(addr_dn, (int)lg);
        int shi = __builtin_amdgcn_ds_bpermute(addr_dn, (int)(lg >> 32));
        shg = __longlong_as_double(((long long)shi << 32) | (unsigned int)slo);
        __builtin_amdgcn_s_setprio(1);
      }
      for (int c = cmax; c >= cmin; --c) {
        const int buf = c & 1;
        if (wv == 1) {
          if (c - 2 >= cmin) stage(c - 2, buf);
        } else if (wv == 2) {
          if (c - 1 >= cmin) regather(c - 1, buf ^ 1);
        } else if (wv == 0) {
          if (c != cmax) {
            double dmax = wave_max64d(fmax(fmax(b0, b1), fmax(b2, b3)));
            long long lm = __double_as_longlong(dmax);
            int ex = (int)((lm >> 52) & 0x7FF);
            double M = __longlong_as_double((long long)(2046 - ex) << 52);
            b0 *= M; b1 *= M; b2 *= M; b3 *= M; g0cur *= M; shg *= M;
            Lacc += (float)(ex - 1023) * LN2;
          }
          const int rhi = (c == cmax) ? ((len - 1) & 15) : FCH - 1;
          const int rlo = max(0, (TS + 1) - 16 * c);
          float4 eH = *(const float4*)&u.fac.Eg[buf][rhi][lane * 4];
          float mH = u.fac.mg[buf][rhi];
          const int r1 = max(rhi - 1, rlo);
          float4 pH = *(const float4*)&u.fac.Eg[buf][r1][lane * 4];
          float pM = u.fac.mg[buf][r1];
          for (int r = rhi; r >= rlo; --r) {
            const int rn = max(r - 2, rlo);
            float4 nH = *(const float4*)&u.fac.Eg[buf][rn][lane * 4];
            float nM = u.fac.mg[buf][rn];
            double g1 = (double)eH.y * b1;
            double g2 = (double)eH.z * b2;
            double g3 = (double)eH.w * b3;
            double nb0 = fma(mv0, g1, sw0 * g0cur);
            double nb1 = fma(mv1, g2, sw1 * g1);
            double nb2 = fma(mv2, g3, sw2 * g2);
            double nb3 = fma(mv3, shg, sw3 * g3);
            double g0n = (double)pH.x * nb0;  // next row's e0 (prefetched)
            long long lg2 = __double_as_longlong(g0n);
            int slo2 = __builtin_amdgcn_ds_bpermute(addr_dn, (int)lg2);
            int shi2 = __builtin_amdgcn_ds_bpermute(addr_dn, (int)(lg2 >> 32));
            b0 = nb0; b1 = nb1; b2 = nb2; b3 = nb3;
            g0cur = g0n;
            shg = __longlong_as_double(((long long)shi2 << 32) |
                                       (unsigned int)slo2);
            Lacc += mH;
            eH = pH; mH = pM; pH = nH; pM = nM;
          }
        }
        __syncthreads();
      }
      if (wv == 0) {
        __builtin_amdgcn_s_setprio(0);
        vecout[lane * 4 + 0] = b0; vecout[lane * 4 + 1] = b1;
        vecout[lane * 4 + 2] = b2; vecout[lane * 4 + 3] = b3;
        if (lane == 0) Lout[b] = Lacc;
      }
    }
    return;
  }

  // ========================= FCC PHASE 1 (MFMA) =========================
  const int sid = bid - 2 * B_;
  const int b = sid >> 5, s = sid & 31;
  const int t0 = 1 + s * CSEG;
  const int len = ilen[b];
  int ke = min(CSEG, T_ - t0);
  ke = min(ke, len - t0);
  if (ke < 0) ke = 0;

#pragma unroll
  for (int i = 0; i < 4; ++i) {
    int f4 = tid + 256 * i;
    int r = f4 >> 4, c4 = f4 & 15;
    int t = t0 + r;
    if (t > T_ - 1) t = T_ - 1;
    float4 v = *(const float4*)(inputs + (size_t)t * (B_ * L_) + b * L_ + c4 * 4);
    *(float4*)(&u.p1.xs[r][c4 * 4]) = v;
  }
  __syncthreads();
#pragma unroll
  for (int rr = 0; rr < 16; ++rr) {
    int r = wv * 16 + rr;
    float v = wave_max64(u.p1.xs[r][lane]);
    if (lane == 0) u.p1.m_arr[r] = v;
  }
  __syncthreads();
#pragma unroll
  for (int i = 0; i < 4; ++i) {
    int f4 = tid + 256 * i;
    int r = f4 >> 4, c4 = f4 & 15;
    float m = u.p1.m_arr[r];
    float4 v = *(float4*)(&u.p1.xs[r][c4 * 4]);
    v.x = __expf(v.x - m); v.y = __expf(v.y - m);
    v.z = __expf(v.z - m); v.w = __expf(v.w - m);
    *(float4*)(&u.p1.xs[r][c4 * 4]) = v;
  }
  for (int i = tid; i < 64 * 68; i += 256) u.p1.P[0][i] = (__bf16)0.0f;
  __syncthreads();
  if (tid < 64) u.p1.P[0][tid * 68 + tid] = (__bf16)1.0f;

  const int ma = wv >> 1, nb = wv & 1;
  const int arow = 32 * ma + (lane & 31);
  const int hh = lane >> 5;
  const int coln = 32 * nb + (lane & 31);
  float Wf[4][8];
#pragma unroll
  for (int kc = 0; kc < 4; ++kc) {
    const float* tp = trans + arow * 64 + kc * 16 + hh * 8;
#pragma unroll
    for (int j = 0; j < 8; ++j) Wf[kc][j] = __expf(tp[j]);
  }

  float lsres = 0.0f;
  int cur = 0;
  for (int k = 0; k < ke; ++k) {
    __syncthreads();
    float scf = 1.0f;
    if ((k & 7) == 0 && k != 0) {
      float mm = fmaxf(fmaxf(u.p1.redmax[0], u.p1.redmax[1]),
                       fmaxf(u.p1.redmax[2], u.p1.redmax[3]));
      scf = __builtin_amdgcn_rcpf(mm);
      lsres += __logf(mm);
    }
    const float srow = u.p1.xs[k][arow] * scf;
    bf16x8 A[4], Bf[4];
    const __bf16* Pc = u.p1.P[cur];
#pragma unroll
    for (int kc = 0; kc < 4; ++kc) {
#pragma unroll
      for (int j = 0; j < 8; ++j) A[kc][j] = (__bf16)(Wf[kc][j] * srow);
      const __bf16* p = Pc + coln * 68 + kc * 16 + hh * 8;
      bf16x4 lo = *(const bf16x4*)p;
      bf16x4 hi = *(const bf16x4*)(p + 4);
      Bf[kc] = __builtin_shufflevector(lo, hi, 0, 1, 2, 3, 4, 5, 6, 7);
    }
    f32x16 acc;
#pragma unroll
    for (int e = 0; e < 16; ++e) acc[e] = 0.0f;
    acc = __builtin_amdgcn_mfma_f32_32x32x16_bf16(A[0], Bf[0], acc, 0, 0, 0);
    acc = __builtin_amdgcn_mfma_f32_32x32x16_bf16(A[1], Bf[1], acc, 0, 0, 0);
    acc = __builtin_amdgcn_mfma_f32_32x32x16_bf16(A[2], Bf[2], acc, 0, 0, 0);
    acc = __builtin_amdgcn_mfma_f32_32x32x16_bf16(A[3], Bf[3], acc, 0, 0, 0);
    __bf16* Pn = u.p1.P[cur ^ 1];
#pragma unroll
    for (int q = 0; q < 4; ++q) {
      const int i0 = 32 * ma + 8 * q + 4 * hh;
      bf16x4 w;
      w[0] = (__bf16)acc[4 * q + 0]; w[1] = (__bf16)acc[4 * q + 1];
      w[2] = (__bf16)acc[4 * q + 2]; w[3] = (__bf16)acc[4 * q + 3];
      *(bf16x4*)(Pn + coln * 68 + i0) = w;
    }
    if ((k & 7) == 7) {
      float mx = acc[0];
#pragma unroll
      for (int e = 1; e < 16; ++e) mx = fmaxf(mx, acc[e]);
      mx = wave_max64(mx);
      if (lane == 0) u.p1.redmax[wv] = mx;
    }
    cur ^= 1;
  }
  __syncthreads();
  __bf16* G = ((__bf16*)ws) + (size_t)sid * 4096;
  const __bf16* Pf = u.p1.P[cur];
  for (int i = tid; i < 4096; i += 256) G[i] = Pf[(i >> 6) * 68 + (i & 63)];
  if (wv == 0) {
    float mt = (lane < ke) ? u.p1.m_arr[lane] : 0.0f;
    float msum = wave_sum64(mt);
    if (lane == 0) scales[sid] = msum + lsres;
  }
}

// K2: per-batch scan over 32 segment matrices (wave0 compute, wave1 stage).
__global__ __launch_bounds__(128) void asg_k2(const float* __restrict__ inputs,
                                              char* __restrict__ ws) {
  __shared__ __align__(16) float Gl[2][64][68];
  __shared__ __align__(16) float Eb[64];
  const int tid = threadIdx.x, lane = tid & 63, wv = tid >> 6;
  const int b = blockIdx.x;
  const __bf16* M = (const __bf16*)ws;
  const float* scales = (const float*)(ws + OFF_SCALE);
  float* full = (float*)(ws + OFF_FULL);

  auto stage = [&](int s, int buf) {
    const __bf16* g = M + ((size_t)(b * NSEG + s)) * 4096 + lane * 64;
#pragma unroll
    for (int q = 0; q < 8; ++q) {
      bf16x8 v = *(const bf16x8*)(g + q * 8);
      float4 f0{(float)v[0], (float)v[1], (float)v[2], (float)v[3]};
      float4 f1{(float)v[4], (float)v[5], (float)v[6], (float)v[7]};
      *(float4*)&Gl[buf][lane][q * 8] = f0;
      *(float4*)&Gl[buf][lane][q * 8 + 4] = f1;
    }
  };

  float Ev = 0.0f, ls = 0.0f;
  if (wv == 0) {
    float x0 = inputs[b * L_ + lane];
    float m0 = wave_max64(x0);
    Ev = __expf(x0 - m0);
    ls = m0;
    Eb[lane] = Ev;
  } else {
    stage(0, 0);
  }
  __syncthreads();
  for (int s = 0; s < NSEG; ++s) {
    if (wv == 1 && s + 1 < NSEG) stage(s + 1, (s + 1) & 1);
    if (wv == 0) {
      const int buf = s & 1;
      float ap0 = 0, ap1 = 0, ap2 = 0, ap3 = 0;
#pragma unroll
      for (int k4 = 0; k4 < 16; ++k4) {
        float4 e4 = *(const float4*)&Eb[k4 * 4];
        ap0 = fmaf(Gl[buf][4 * k4 + 0][lane], e4.x, ap0);
        ap1 = fmaf(Gl[buf][4 * k4 + 1][lane], e4.y, ap1);
        ap2 = fmaf(Gl[buf][4 * k4 + 2][lane], e4.z, ap2);
        ap3 = fmaf(Gl[buf][4 * k4 + 3][lane], e4.w, ap3);
      }
      float ap = (ap0 + ap1) + (ap2 + ap3);
      float mx = wave_max64(ap);
      float sc = __builtin_amdgcn_rcpf(mx);
      Ev = ap * sc;
      Eb[lane] = Ev;
      ls += __logf(mx) + scales[b * NSEG + s];
    }
    __syncthreads();
  }
  if (wv == 0) {
    float ssum = wave_sum64(Ev);
    if (lane == 0) full[b] = ls + __logf(ssum);
  }
}

// K3: per-batch dot(fwd,bwd) in f64, log-combine, mean over batches.
__global__ __launch_bounds__(256) void asg_k3(const char* __restrict__ ws,
                                              float* __restrict__ out) {
  __shared__ float diff[64];
  const int tid = threadIdx.x;
  const int b = tid >> 2, q = tid & 3;
  const double* fv = (const double*)(ws + OFF_FWD) + b * 256;
  const double* bv = (const double*)(ws + OFF_BWD) + b * 256;
  const float* full = (const float*)(ws + OFF_FULL);
  const float* Lf = (const float*)(ws + OFF_LF);
  const float* Lb = (const float*)(ws + OFF_LB);

  double s = 0.0;
  for (int j = q * 64; j < q * 64 + 64; ++j) s += fv[j] * bv[j];
  s += __shfl_xor(s, 1, 64);
  s += __shfl_xor(s, 2, 64);
  if (q == 0) {
    s = fmax(s, 1e-300);
    long long ls = __double_as_longlong(s);
    int ex = (int)((ls >> 52) & 0x7FF);
    double mant = __longlong_as_double((ls & 0xFFFFFFFFFFFFFLL) |
                                       (1023LL << 52));
    float alig = Lf[b] + Lb[b] + (float)(ex - 1023) * LN2 + __logf((float)mant);
    diff[b] = full[b] - alig;
  }
  __syncthreads();
  if (tid < 64) {
    float d = diff[tid];
    d = wave_sum64(d);
    if (tid == 0) out[0] = d * (1.0f / 64.0f);
  }
}

extern "C" void kernel_launch(void* const* d_in, const int* in_sizes, int n_in,
                              void* d_out, int out_size, void* d_ws,
                              size_t ws_size, hipStream_t stream) {
  const float* inputs = (const float*)d_in[0];
  const float* trans = (const float*)d_in[1];
  const int* targets = (const int*)d_in[2];
  const int* ilen = (const int*)d_in[3];
  const int* tlen = (const int*)d_in[4];
  char* ws = (char*)d_ws;
  float* out = (float*)d_out;

  hipLaunchKernelGGL(asg_k1, dim3(2 * B_ + NSEG * B_), dim3(256), 0, stream,
                     inputs, trans, targets, ilen, tlen, ws);
  hipLaunchKernelGGL(asg_k2, dim3(B_), dim3(128), 0, stream, inputs, ws);
  hipLaunchKernelGGL(asg_k3, dim3(1), dim3(256), 0, stream, ws, out);
}